// Round 1
// baseline (4735.958 us; speedup 1.0000x reference)
//
#include <hip/hip_runtime.h>
#include <math.h>

#define BB 4
#define NN 4096
#define DD 256
#define HC 8
#define HK 32
#define DD2 512
#define CC2 1024
#define UPD 128

static constexpr int ROWS = BB * NN;  // 16384

// workspace offsets (in floats); peak = 40M floats = 160 MB
static constexpr size_t OFF_X1E = 0;                    // 4M floats, live k1..k6
static constexpr size_t OFF_N1  = 4u * 1024 * 1024;     // n1 (k1..k4), then attT (k5..k6)
static constexpr size_t OFF_N2  = 8u * 1024 * 1024;     // 4M, live k2..k5
static constexpr size_t OFF_KMAX = 12u * 1024 * 1024;   // 1024
static constexpr size_t OFF_KSUM = OFF_KMAX + 1024;     // 1024
static constexpr size_t OFF_CTX  = OFF_KMAX + 2048;     // 32768
static constexpr size_t OFF_TX  = 16u * 1024 * 1024;    // 8M, live k6..k8
static constexpr size_t OFF_H   = 24u * 1024 * 1024;    // 16M, live k7..k8
static constexpr size_t OFF_MX  = 0;                    // reuse x1e region (dead), 8M

// ---------------- k1: x1e = x1 @ w_x1 + b_x1 ; n1 = LN(x1e) ----------------
__global__ __launch_bounds__(256) void k1_x1lin_ln(
    const float* __restrict__ x1, const float* __restrict__ w,
    const float* __restrict__ bias, const float* __restrict__ g,
    const float* __restrict__ be, float* __restrict__ x1e,
    float* __restrict__ n1) {
  const int row = blockIdx.x, t = threadIdx.x;
  __shared__ float xr[DD];
  __shared__ float red[256];
  xr[t] = x1[(size_t)row * DD + t];
  __syncthreads();
  float acc = bias[t];
  for (int d = 0; d < DD; ++d) acc += xr[d] * w[d * DD + t];
  x1e[(size_t)row * DD + t] = acc;
  red[t] = acc; __syncthreads();
  for (int s = 128; s > 0; s >>= 1) { if (t < s) red[t] += red[t + s]; __syncthreads(); }
  float mean = red[0] * (1.0f / DD); __syncthreads();
  float dv = acc - mean;
  red[t] = dv * dv; __syncthreads();
  for (int s = 128; s > 0; s >>= 1) { if (t < s) red[t] += red[t + s]; __syncthreads(); }
  float inv = rsqrtf(red[0] * (1.0f / DD) + 1e-5f);
  n1[(size_t)row * DD + t] = dv * inv * g[t] + be[t];
}

// ---------------- k2: n2 = LN(x2) ----------------
__global__ __launch_bounds__(256) void k2_ln_x2(
    const float* __restrict__ x2, const float* __restrict__ g,
    const float* __restrict__ be, float* __restrict__ n2) {
  const int row = blockIdx.x, t = threadIdx.x;
  __shared__ float red[256];
  float v = x2[(size_t)row * DD + t];
  red[t] = v; __syncthreads();
  for (int s = 128; s > 0; s >>= 1) { if (t < s) red[t] += red[t + s]; __syncthreads(); }
  float mean = red[0] * (1.0f / DD); __syncthreads();
  float dv = v - mean;
  red[t] = dv * dv; __syncthreads();
  for (int s = 128; s > 0; s >>= 1) { if (t < s) red[t] += red[t + s]; __syncthreads(); }
  float inv = rsqrtf(red[0] * (1.0f / DD) + 1e-5f);
  n2[(size_t)row * DD + t] = dv * inv * g[t] + be[t];
}

// ---------------- k3: per-(b,d) column softmax stats over tokens ----------------
__global__ __launch_bounds__(256) void k3_kstats(
    const float* __restrict__ n2, float* __restrict__ kmax,
    float* __restrict__ ksum) {
  const int b = blockIdx.x >> 8, d = blockIdx.x & 255, t = threadIdx.x;
  float vals[16];
  float mx = -1e30f;
  for (int i = 0; i < 16; ++i) {
    float v = n2[((size_t)b * NN + (i * 256 + t)) * DD + d];
    vals[i] = v; mx = fmaxf(mx, v);
  }
  __shared__ float red[256];
  red[t] = mx; __syncthreads();
  for (int s = 128; s > 0; s >>= 1) { if (t < s) red[t] = fmaxf(red[t], red[t + s]); __syncthreads(); }
  mx = red[0]; __syncthreads();
  float sm = 0.f;
  for (int i = 0; i < 16; ++i) sm += expf(vals[i] - mx);
  red[t] = sm; __syncthreads();
  for (int s = 128; s > 0; s >>= 1) { if (t < s) red[t] += red[t + s]; __syncthreads(); }
  if (t == 0) { kmax[blockIdx.x] = mx; ksum[blockIdx.x] = red[0]; }
}

// ---------------- k4: ctx[b,h,k,v] = sum_n softmaxK * n1 ----------------
__global__ __launch_bounds__(256) void k4_ctx(
    const float* __restrict__ n1, const float* __restrict__ n2,
    const float* __restrict__ kmax, const float* __restrict__ ksum,
    float* __restrict__ ctx) {
  const int bx = blockIdx.x;
  const int b = bx >> 8, h = (bx >> 5) & 7, kk = bx & 31;
  const int t = threadIdx.x;
  const int dk = h * HK + kk;
  const float mx = kmax[b * DD + dk];
  const float inv = 1.0f / ksum[b * DD + dk];
  float acc[32];
  #pragma unroll
  for (int v = 0; v < 32; ++v) acc[v] = 0.f;
  for (int i = 0; i < 16; ++i) {
    const int n = i * 256 + t;
    const size_t base = ((size_t)b * NN + n) * DD;
    const float kv = expf(n2[base + dk] - mx) * inv;
    const float* v1 = n1 + base + h * HK;
    #pragma unroll
    for (int v = 0; v < 32; ++v) acc[v] += kv * v1[v];
  }
  __shared__ float sm[256 * 32];
  #pragma unroll
  for (int v = 0; v < 32; ++v) sm[t * 32 + v] = acc[v];
  __syncthreads();
  for (int s = 128; s > 0; s >>= 1) {
    if (t < s) {
      #pragma unroll
      for (int v = 0; v < 32; ++v) sm[t * 32 + v] += sm[(t + s) * 32 + v];
    }
    __syncthreads();
  }
  if (t < 32) ctx[(((size_t)b * 8 + h) * 32 + kk) * 32 + t] = sm[t];
}

// ---------------- k5: attT[b,n,d] = sum_k ctx[b,h,k,v] * q[b,h,k,n] ----------------
__global__ __launch_bounds__(256) void k5_attT(
    const float* __restrict__ n2, const float* __restrict__ ctx,
    float* __restrict__ attT) {
  const int row = blockIdx.x, t = threadIdx.x;
  const int b = row >> 12;
  const int h = t >> 5, v = t & 31;
  __shared__ float nr[DD];
  __shared__ float q[DD];
  nr[t] = n2[(size_t)row * DD + t];
  __syncthreads();
  float mx = -1e30f;
  for (int c = 0; c < 32; ++c) mx = fmaxf(mx, nr[h * 32 + c]);
  float sm = 0.f;
  for (int c = 0; c < 32; ++c) sm += expf(nr[h * 32 + c] - mx);
  q[t] = expf(nr[t] - mx) / sm;
  __syncthreads();
  const float* cb = ctx + ((size_t)(b * 8 + h) * 32) * 32 + v;  // stride 32 over k
  float acc = 0.f;
  #pragma unroll
  for (int k = 0; k < 32; ++k) acc += cb[k * 32] * q[h * 32 + k];
  attT[(size_t)row * DD + t] = acc;
}

// ---------------- k6: rep = LN(attT @ w_rep + b_rep); tx = concat(x1e,x2)+rep ----------------
__global__ __launch_bounds__(256) void k6_reptx(
    const float* __restrict__ attT, const float* __restrict__ x1e,
    const float* __restrict__ x2, const float* __restrict__ w_rep,
    const float* __restrict__ b_rep, const float* __restrict__ g_an,
    const float* __restrict__ be_an, float* __restrict__ tx) {
  const int row = blockIdx.x, t = threadIdx.x;
  __shared__ float ar[DD];
  __shared__ float red[256];
  ar[t] = attT[(size_t)row * DD + t];
  __syncthreads();
  float a0 = b_rep[t], a1 = b_rep[t + 256];
  for (int d = 0; d < DD; ++d) {
    float x = ar[d];
    a0 += x * w_rep[d * DD2 + t];
    a1 += x * w_rep[d * DD2 + t + 256];
  }
  red[t] = a0 + a1; __syncthreads();
  for (int s = 128; s > 0; s >>= 1) { if (t < s) red[t] += red[t + s]; __syncthreads(); }
  float mean = red[0] * (1.0f / DD2); __syncthreads();
  float d0 = a0 - mean, d1 = a1 - mean;
  red[t] = d0 * d0 + d1 * d1; __syncthreads();
  for (int s = 128; s > 0; s >>= 1) { if (t < s) red[t] += red[t + s]; __syncthreads(); }
  float inv = rsqrtf(red[0] * (1.0f / DD2) + 1e-5f);
  float r0 = d0 * inv * g_an[t] + be_an[t];
  float r1 = d1 * inv * g_an[t + 256] + be_an[t + 256];
  tx[(size_t)row * DD2 + t] = x1e[(size_t)row * DD + t] + r0;
  tx[(size_t)row * DD2 + t + 256] = x2[(size_t)row * DD + t] + r1;
}

// ---------------- k7: h = LN(tx; g_n2) @ w_fc1 + b_fc1 ----------------
__global__ __launch_bounds__(256) void k7_fc1(
    const float* __restrict__ tx, const float* __restrict__ g,
    const float* __restrict__ be, const float* __restrict__ w_fc1,
    const float* __restrict__ b_fc1, float* __restrict__ h) {
  const int row = blockIdx.x, t = threadIdx.x;
  __shared__ float xr[DD2];
  __shared__ float red[256];
  float v0 = tx[(size_t)row * DD2 + t], v1 = tx[(size_t)row * DD2 + t + 256];
  red[t] = v0 + v1; __syncthreads();
  for (int s = 128; s > 0; s >>= 1) { if (t < s) red[t] += red[t + s]; __syncthreads(); }
  float mean = red[0] * (1.0f / DD2); __syncthreads();
  float d0 = v0 - mean, d1 = v1 - mean;
  red[t] = d0 * d0 + d1 * d1; __syncthreads();
  for (int s = 128; s > 0; s >>= 1) { if (t < s) red[t] += red[t + s]; __syncthreads(); }
  float inv = rsqrtf(red[0] * (1.0f / DD2) + 1e-5f);
  xr[t] = d0 * inv * g[t] + be[t];
  xr[t + 256] = d1 * inv * g[t + 256] + be[t + 256];
  __syncthreads();
  float a[4];
  #pragma unroll
  for (int j = 0; j < 4; ++j) a[j] = b_fc1[t + 256 * j];
  for (int d = 0; d < DD2; ++d) {
    float xv = xr[d];
    #pragma unroll
    for (int j = 0; j < 4; ++j) a[j] += xv * w_fc1[d * CC2 + t + 256 * j];
  }
  #pragma unroll
  for (int j = 0; j < 4; ++j) h[(size_t)row * CC2 + t + 256 * j] = a[j];
}

// ------- k8: dw-conv3d + skip + LN + GELU, then mx = tx + ax @ w_fc2 + b_fc2 -------
__global__ __launch_bounds__(256) void k8_conv_ffn2(
    const float* __restrict__ h, const float* __restrict__ tx,
    const float* __restrict__ w_dw, const float* __restrict__ b_dw,
    const float* __restrict__ g, const float* __restrict__ be,
    const float* __restrict__ w_fc2, const float* __restrict__ b_fc2,
    float* __restrict__ mx) {
  const int row = blockIdx.x, t = threadIdx.x;
  const int b = row >> 12, n = row & (NN - 1);
  const int z = n >> 8, y = (n >> 4) & 15, x = n & 15;
  __shared__ float axr[CC2];
  __shared__ float red[256];
  float acc[4];
  #pragma unroll
  for (int j = 0; j < 4; ++j) acc[j] = b_dw[t + 256 * j];
  const size_t hb = (size_t)b * NN * CC2;
  for (int dz = -1; dz <= 1; ++dz) {
    int zz = z + dz; if (zz < 0 || zz > 15) continue;
    for (int dy = -1; dy <= 1; ++dy) {
      int yy = y + dy; if (yy < 0 || yy > 15) continue;
      for (int dx = -1; dx <= 1; ++dx) {
        int xx = x + dx; if (xx < 0 || xx > 15) continue;
        int np = (zz << 8) | (yy << 4) | xx;
        int widx = (dz + 1) * 9 + (dy + 1) * 3 + (dx + 1);
        const float* hp = h + hb + (size_t)np * CC2;
        #pragma unroll
        for (int j = 0; j < 4; ++j)
          acc[j] += hp[t + 256 * j] * w_dw[(t + 256 * j) * 27 + widx];
      }
    }
  }
  float v[4];
  float ssum = 0.f;
  #pragma unroll
  for (int j = 0; j < 4; ++j) {
    v[j] = acc[j] + h[hb + (size_t)n * CC2 + t + 256 * j];
    ssum += v[j];
  }
  red[t] = ssum; __syncthreads();
  for (int s = 128; s > 0; s >>= 1) { if (t < s) red[t] += red[t + s]; __syncthreads(); }
  float mean = red[0] * (1.0f / CC2); __syncthreads();
  float sq = 0.f;
  #pragma unroll
  for (int j = 0; j < 4; ++j) { v[j] -= mean; sq += v[j] * v[j]; }
  red[t] = sq; __syncthreads();
  for (int s = 128; s > 0; s >>= 1) { if (t < s) red[t] += red[t + s]; __syncthreads(); }
  float inv = rsqrtf(red[0] * (1.0f / CC2) + 1e-5f);
  #pragma unroll
  for (int j = 0; j < 4; ++j) {
    float u = v[j] * inv * g[t + 256 * j] + be[t + 256 * j];
    axr[t + 256 * j] = 0.5f * u * (1.0f + erff(u * 0.70710678118654752f));
  }
  __syncthreads();
  float a0 = b_fc2[t], a1 = b_fc2[t + 256];
  for (int d = 0; d < CC2; ++d) {
    float a = axr[d];
    a0 += a * w_fc2[d * DD2 + t];
    a1 += a * w_fc2[d * DD2 + t + 256];
  }
  mx[(size_t)row * DD2 + t] = tx[(size_t)row * DD2 + t] + a0;
  mx[(size_t)row * DD2 + t + 256] = tx[(size_t)row * DD2 + t + 256] + a1;
}

// ------- k9: y = mx@w_cat+b_cat; ye = y@w_exp; out = LN128(ye; g_up,be_up) -------
__global__ __launch_bounds__(256) void k9_out(
    const float* __restrict__ mx, const float* __restrict__ w_cat,
    const float* __restrict__ b_cat, const float* __restrict__ w_exp,
    const float* __restrict__ g_up, const float* __restrict__ be_up,
    float* __restrict__ out) {
  const int row = blockIdx.x, t = threadIdx.x;
  __shared__ float mr[DD2];
  __shared__ float yr[DD];
  __shared__ float red[256], red2[256];
  mr[t] = mx[(size_t)row * DD2 + t];
  mr[t + 256] = mx[(size_t)row * DD2 + t + 256];
  __syncthreads();
  float acc = b_cat[t];
  for (int d = 0; d < DD2; ++d) acc += mr[d] * w_cat[d * DD + t];
  yr[t] = acc;
  __syncthreads();
  float4 ye = make_float4(0.f, 0.f, 0.f, 0.f);
  for (int d = 0; d < DD; ++d) {
    float yv = yr[d];
    float4 w4 = reinterpret_cast<const float4*>(w_exp)[d * 256 + t];
    ye.x += yv * w4.x; ye.y += yv * w4.y; ye.z += yv * w4.z; ye.w += yv * w4.w;
  }
  float s1 = ye.x + ye.y + ye.z + ye.w;
  float s2 = ye.x * ye.x + ye.y * ye.y + ye.z * ye.z + ye.w * ye.w;
  red[t] = s1; red2[t] = s2; __syncthreads();
  const int lane = t & 31;
  for (int s = 16; s > 0; s >>= 1) {
    if (lane < s) { red[t] += red[t + s]; red2[t] += red2[t + s]; }
    __syncthreads();
  }
  const int gbase = t & ~31;
  float mean = red[gbase] * (1.0f / UPD);
  float var = red2[gbase] * (1.0f / UPD) - mean * mean;
  float inv = rsqrtf(var + 1e-5f);
  const int grp = t >> 5;
  const int j0 = (t & 31) * 4;
  size_t ob = ((size_t)row * 8 + grp) * UPD + j0;
  out[ob]     = (ye.x - mean) * inv * g_up[j0]     + be_up[j0];
  out[ob + 1] = (ye.y - mean) * inv * g_up[j0 + 1] + be_up[j0 + 1];
  out[ob + 2] = (ye.z - mean) * inv * g_up[j0 + 2] + be_up[j0 + 2];
  out[ob + 3] = (ye.w - mean) * inv * g_up[j0 + 3] + be_up[j0 + 3];
}

extern "C" void kernel_launch(void* const* d_in, const int* in_sizes, int n_in,
                              void* d_out, int out_size, void* d_ws, size_t ws_size,
                              hipStream_t stream) {
  const float* x1    = (const float*)d_in[0];
  const float* x2    = (const float*)d_in[1];
  const float* w_x1  = (const float*)d_in[2];
  const float* b_x1  = (const float*)d_in[3];
  const float* g_n1  = (const float*)d_in[4];
  const float* be_n1 = (const float*)d_in[5];
  const float* w_rep = (const float*)d_in[6];
  const float* b_rep = (const float*)d_in[7];
  const float* g_an  = (const float*)d_in[8];
  const float* be_an = (const float*)d_in[9];
  const float* g_n2  = (const float*)d_in[10];
  const float* be_n2 = (const float*)d_in[11];
  const float* w_fc1 = (const float*)d_in[12];
  const float* b_fc1 = (const float*)d_in[13];
  const float* w_dw  = (const float*)d_in[14];
  const float* b_dw  = (const float*)d_in[15];
  const float* g_m1  = (const float*)d_in[16];
  const float* be_m1 = (const float*)d_in[17];
  const float* w_fc2 = (const float*)d_in[18];
  const float* b_fc2 = (const float*)d_in[19];
  const float* w_cat = (const float*)d_in[20];
  const float* b_cat = (const float*)d_in[21];
  const float* w_exp = (const float*)d_in[22];
  const float* g_up  = (const float*)d_in[23];
  const float* be_up = (const float*)d_in[24];

  float* ws  = (float*)d_ws;
  float* out = (float*)d_out;

  float* x1e  = ws + OFF_X1E;
  float* n1   = ws + OFF_N1;
  float* n2   = ws + OFF_N2;
  float* kmax = ws + OFF_KMAX;
  float* ksum = ws + OFF_KSUM;
  float* ctx  = ws + OFF_CTX;
  float* attT = ws + OFF_N1;   // reuse n1 (dead after k4)
  float* tx   = ws + OFF_TX;
  float* h    = ws + OFF_H;
  float* mx   = ws + OFF_MX;   // reuse x1e region (dead after k6)

  k1_x1lin_ln<<<ROWS, 256, 0, stream>>>(x1, w_x1, b_x1, g_n1, be_n1, x1e, n1);
  k2_ln_x2<<<ROWS, 256, 0, stream>>>(x2, g_n1, be_n1, n2);
  k3_kstats<<<BB * DD, 256, 0, stream>>>(n2, kmax, ksum);
  k4_ctx<<<BB * HC * HK, 256, 0, stream>>>(n1, n2, kmax, ksum, ctx);
  k5_attT<<<ROWS, 256, 0, stream>>>(n2, ctx, attT);
  k6_reptx<<<ROWS, 256, 0, stream>>>(attT, x1e, x2, w_rep, b_rep, g_an, be_an, tx);
  k7_fc1<<<ROWS, 256, 0, stream>>>(tx, g_n2, be_n2, w_fc1, b_fc1, h);
  k8_conv_ffn2<<<ROWS, 256, 0, stream>>>(h, tx, w_dw, b_dw, g_m1, be_m1, w_fc2, b_fc2, mx);
  k9_out<<<ROWS, 256, 0, stream>>>(mx, w_cat, b_cat, w_exp, g_up, be_up, out);
}

// Round 2
// 1519.262 us; speedup vs baseline: 3.1173x; 3.1173x over previous
//
#include <hip/hip_runtime.h>
#include <math.h>

using u16 = unsigned short;
typedef __bf16 bf16x8 __attribute__((ext_vector_type(8)));
typedef float f32x4 __attribute__((ext_vector_type(4)));

#define BB 4
#define NN 4096
#define DD 256
#define DD2 512
#define CC2 1024
static constexpr int ROWS = BB * NN;  // 16384
static constexpr size_t MB = 1024 * 1024;

// ---- workspace layout (bytes) ----
// 0   ..8M   : x1b (bf16) -> attT (bf16) -> y (bf16)
// 8M  ..24M  : x1e (f32)  -> mx (bf16)
// 24M ..32M  : n1 (bf16)
// 32M ..48M  : n2 (f32)
// 48M ..49M  : kmax/ksum/ctx (f32)
// 49M ..81M  : rep_raw (f32) -> ax (bf16); ye (f32) spans 49M..113M
// 81M ..97M  : tx (bf16)
// 97M ..113M : txln (bf16)
// 113M..145M : h (bf16)
// 145M..149M : transposed bf16 weights
// peak ~148.2 MB (round-0 used 160 MB OK)

__device__ __forceinline__ u16 f2bf(float f) {
  union { float f; unsigned u; } v; v.f = f;
  unsigned r = v.u + 0x7fffu + ((v.u >> 16) & 1u);
  return (u16)(r >> 16);
}
__device__ __forceinline__ float bf2f(u16 u) {
  union { unsigned u; float f; } v; v.u = ((unsigned)u) << 16;
  return v.f;
}
__device__ __forceinline__ float u2f(unsigned x) {
  union { unsigned u; float f; } v; v.u = x; return v.f;
}

// ---------------- weight transpose + cast: out[n*K+k] = in[k*N+n] ----------------
__global__ __launch_bounds__(256) void wconv_t(const float* __restrict__ in,
                                               u16* __restrict__ out,
                                               int K, int N) {
  int i = blockIdx.x * 256 + threadIdx.x;
  if (i >= K * N) return;
  int n = i / K, k = i - n * K;
  out[i] = f2bf(in[(size_t)k * N + n]);
}

// ---------------- cast fp32 -> bf16, 8 elems/thread ----------------
__global__ __launch_bounds__(256) void cast8(const float* __restrict__ in,
                                             u16* __restrict__ out, int n8) {
  int i = blockIdx.x * 256 + threadIdx.x;
  if (i >= n8) return;
  float4 a = reinterpret_cast<const float4*>(in)[i * 2];
  float4 b = reinterpret_cast<const float4*>(in)[i * 2 + 1];
  u16 o[8] = {f2bf(a.x), f2bf(a.y), f2bf(a.z), f2bf(a.w),
              f2bf(b.x), f2bf(b.y), f2bf(b.z), f2bf(b.w)};
  reinterpret_cast<uint4*>(out)[i] = *reinterpret_cast<uint4*>(o);
}

// ---------------- generic 128x128-tile MFMA GEMM ----------------
// A [M][K] bf16, Bt [N][K] bf16, C row-major [M][Ncols]
// EPI: 0 = f32 out, 1 = bf16 out, 2 = bf16 out with bf16 residual add
template <int K, int EPI>
__global__ __launch_bounds__(256, 2) void gemm_mfma(
    const u16* __restrict__ A, const u16* __restrict__ Bt,
    const float* __restrict__ bias, const u16* __restrict__ resid,
    void* __restrict__ Cout, int nTilesN) {
  const int t = threadIdx.x;
  const int m0 = (blockIdx.x / nTilesN) * 128;
  const int n0 = (blockIdx.x % nTilesN) * 128;
  const int Ncols = nTilesN * 128;
  const int lane = t & 63, wid = t >> 6;
  const int wr = wid >> 1, wc = wid & 1;
  const int lrow = lane & 15, kgrp = lane >> 4;

  __shared__ u16 ldsA[2][128 * 32];
  __shared__ u16 ldsB[2][128 * 32];

  // staging map: lds (row, slot) holds global k-chunk (slot ^ ((row>>1)&3))
  int srow[2], sslot[2];
#pragma unroll
  for (int c = 0; c < 2; ++c) {
    int idx = c * 256 + t;
    srow[c] = idx >> 2;
    sslot[c] = (idx & 3) ^ ((srow[c] >> 1) & 3);
  }

  int offA[4], offB[4];
#pragma unroll
  for (int m = 0; m < 4; ++m) {
    int r = wr * 64 + m * 16 + lrow;
    offA[m] = r * 32 + ((kgrp ^ ((r >> 1) & 3)) * 8);
  }
#pragma unroll
  for (int n = 0; n < 4; ++n) {
    int r = wc * 64 + n * 16 + lrow;
    offB[n] = r * 32 + ((kgrp ^ ((r >> 1) & 3)) * 8);
  }

  f32x4 acc[4][4];
#pragma unroll
  for (int m = 0; m < 4; ++m)
#pragma unroll
    for (int n = 0; n < 4; ++n) acc[m][n] = f32x4{0.f, 0.f, 0.f, 0.f};

  uint4 ra[2], rb[2];
#pragma unroll
  for (int c = 0; c < 2; ++c) {
    ra[c] = *(const uint4*)(A + (size_t)(m0 + srow[c]) * K + sslot[c] * 8);
    rb[c] = *(const uint4*)(Bt + (size_t)(n0 + srow[c]) * K + sslot[c] * 8);
  }
#pragma unroll
  for (int c = 0; c < 2; ++c) {
    int idx = c * 256 + t;
    *(uint4*)&ldsA[0][idx * 8] = ra[c];
    *(uint4*)&ldsB[0][idx * 8] = rb[c];
  }
  __syncthreads();

  const int nt = K / 32;
  for (int tt = 0; tt < nt; ++tt) {
    const int cur = tt & 1;
    if (tt + 1 < nt) {
      const int kc = (tt + 1) * 32;
#pragma unroll
      for (int c = 0; c < 2; ++c) {
        ra[c] = *(const uint4*)(A + (size_t)(m0 + srow[c]) * K + kc + sslot[c] * 8);
        rb[c] = *(const uint4*)(Bt + (size_t)(n0 + srow[c]) * K + kc + sslot[c] * 8);
      }
    }
    bf16x8 af[4], bf[4];
#pragma unroll
    for (int m = 0; m < 4; ++m) af[m] = *(const bf16x8*)&ldsA[cur][offA[m]];
#pragma unroll
    for (int n = 0; n < 4; ++n) bf[n] = *(const bf16x8*)&ldsB[cur][offB[n]];
#pragma unroll
    for (int m = 0; m < 4; ++m)
#pragma unroll
      for (int n = 0; n < 4; ++n)
        acc[m][n] = __builtin_amdgcn_mfma_f32_16x16x32_bf16(af[m], bf[n], acc[m][n], 0, 0, 0);
    if (tt + 1 < nt) {
#pragma unroll
      for (int c = 0; c < 2; ++c) {
        int idx = c * 256 + t;
        *(uint4*)&ldsA[cur ^ 1][idx * 8] = ra[c];
        *(uint4*)&ldsB[cur ^ 1][idx * 8] = rb[c];
      }
    }
    __syncthreads();
  }

  // epilogue: D layout col=lane&15, row=(lane>>4)*4+j
  float bcol[4];
#pragma unroll
  for (int n = 0; n < 4; ++n) {
    int col = n0 + wc * 64 + n * 16 + (lane & 15);
    bcol[n] = bias ? bias[col] : 0.f;
  }
#pragma unroll
  for (int m = 0; m < 4; ++m) {
    const int r0 = m0 + wr * 64 + m * 16 + kgrp * 4;
#pragma unroll
    for (int n = 0; n < 4; ++n) {
      const int col = n0 + wc * 64 + n * 16 + (lane & 15);
#pragma unroll
      for (int j = 0; j < 4; ++j) {
        float v = acc[m][n][j] + bcol[n];
        size_t idx = (size_t)(r0 + j) * Ncols + col;
        if (EPI == 0) {
          ((float*)Cout)[idx] = v;
        } else if (EPI == 1) {
          ((u16*)Cout)[idx] = f2bf(v);
        } else {
          v += bf2f(resid[idx]);
          ((u16*)Cout)[idx] = f2bf(v);
        }
      }
    }
  }
}

// ---------------- per-row LN over 256, optional bf16 out ----------------
template <bool OBF>
__global__ __launch_bounds__(256) void ln256(const float* __restrict__ in,
                                             const float* __restrict__ g,
                                             const float* __restrict__ be,
                                             void* __restrict__ out) {
  const int row = blockIdx.x, t = threadIdx.x;
  __shared__ float red[256];
  float v = in[(size_t)row * DD + t];
  red[t] = v; __syncthreads();
  for (int s = 128; s > 0; s >>= 1) { if (t < s) red[t] += red[t + s]; __syncthreads(); }
  float mean = red[0] * (1.0f / DD); __syncthreads();
  float dv = v - mean;
  red[t] = dv * dv; __syncthreads();
  for (int s = 128; s > 0; s >>= 1) { if (t < s) red[t] += red[t + s]; __syncthreads(); }
  float inv = rsqrtf(red[0] * (1.0f / DD) + 1e-5f);
  float r = dv * inv * g[t] + be[t];
  if (OBF) ((u16*)out)[(size_t)row * DD + t] = f2bf(r);
  else ((float*)out)[(size_t)row * DD + t] = r;
}

// ---------------- k3: per-(b,d) column softmax stats over tokens ----------------
__global__ __launch_bounds__(256) void k3_kstats(
    const float* __restrict__ n2, float* __restrict__ kmax,
    float* __restrict__ ksum) {
  const int b = blockIdx.x >> 8, d = blockIdx.x & 255, t = threadIdx.x;
  float vals[16];
  float mx = -1e30f;
  for (int i = 0; i < 16; ++i) {
    float v = n2[((size_t)b * NN + (i * 256 + t)) * DD + d];
    vals[i] = v; mx = fmaxf(mx, v);
  }
  __shared__ float red[256];
  red[t] = mx; __syncthreads();
  for (int s = 128; s > 0; s >>= 1) { if (t < s) red[t] = fmaxf(red[t], red[t + s]); __syncthreads(); }
  mx = red[0]; __syncthreads();
  float sm = 0.f;
  for (int i = 0; i < 16; ++i) sm += expf(vals[i] - mx);
  red[t] = sm; __syncthreads();
  for (int s = 128; s > 0; s >>= 1) { if (t < s) red[t] += red[t + s]; __syncthreads(); }
  if (t == 0) { kmax[blockIdx.x] = mx; ksum[blockIdx.x] = red[0]; }
}

// ---------------- k4: ctx[b,h,k,v] = sum_n softmaxK(n2) * n1 ----------------
__global__ __launch_bounds__(256) void k4_ctx(
    const u16* __restrict__ n1, const float* __restrict__ n2,
    const float* __restrict__ kmax, const float* __restrict__ ksum,
    float* __restrict__ ctx) {
  const int bx = blockIdx.x;
  const int b = bx >> 8, h = (bx >> 5) & 7, kk = bx & 31;
  const int t = threadIdx.x;
  const int dk = h * 32 + kk;
  const float mx = kmax[b * DD + dk];
  const float inv = 1.0f / ksum[b * DD + dk];
  float acc[32];
#pragma unroll
  for (int v = 0; v < 32; ++v) acc[v] = 0.f;
  for (int i = 0; i < 16; ++i) {
    const int n = i * 256 + t;
    const size_t base = ((size_t)b * NN + n) * DD;
    const float kv = expf(n2[base + dk] - mx) * inv;
    const u16* v1 = n1 + base + h * 32;
#pragma unroll
    for (int q = 0; q < 4; ++q) {
      uint4 u = *(const uint4*)(v1 + q * 8);
      unsigned w[4] = {u.x, u.y, u.z, u.w};
#pragma unroll
      for (int p = 0; p < 4; ++p) {
        acc[q * 8 + p * 2]     += kv * u2f(w[p] << 16);
        acc[q * 8 + p * 2 + 1] += kv * u2f(w[p] & 0xffff0000u);
      }
    }
  }
  __shared__ float sm[256 * 32];
#pragma unroll
  for (int v = 0; v < 32; ++v) sm[t * 32 + v] = acc[v];
  __syncthreads();
  for (int s = 128; s > 0; s >>= 1) {
    if (t < s) {
#pragma unroll
      for (int v = 0; v < 32; ++v) sm[t * 32 + v] += sm[(t + s) * 32 + v];
    }
    __syncthreads();
  }
  if (t < 32) ctx[(((size_t)b * 8 + h) * 32 + kk) * 32 + t] = sm[t];
}

// ---------------- k5: attT[b,n,d] = sum_k ctx * softmaxQ ----------------
__global__ __launch_bounds__(256) void k5_attT(
    const float* __restrict__ n2, const float* __restrict__ ctx,
    u16* __restrict__ attT) {
  const int row = blockIdx.x, t = threadIdx.x;
  const int b = row >> 12;
  const int h = t >> 5, v = t & 31;
  __shared__ float nr[DD];
  __shared__ float q[DD];
  nr[t] = n2[(size_t)row * DD + t];
  __syncthreads();
  float mx = -1e30f;
  for (int c = 0; c < 32; ++c) mx = fmaxf(mx, nr[h * 32 + c]);
  float sm = 0.f;
  for (int c = 0; c < 32; ++c) sm += expf(nr[h * 32 + c] - mx);
  q[t] = expf(nr[t] - mx) / sm;
  __syncthreads();
  const float* cb = ctx + ((size_t)(b * 8 + h) * 32) * 32 + v;
  float acc = 0.f;
#pragma unroll
  for (int k = 0; k < 32; ++k) acc += cb[k * 32] * q[h * 32 + k];
  attT[(size_t)row * DD + t] = f2bf(acc);
}

// ------- l3: rep = LN(rep_raw); tx = concat(x1e,x2)+rep (bf16); txln = LN(tx) bf16 -------
__global__ __launch_bounds__(256) void l3_reptx(
    const float* __restrict__ rep_raw, const float* __restrict__ x1e,
    const float* __restrict__ x2,
    const float* __restrict__ g_an, const float* __restrict__ be_an,
    const float* __restrict__ g_n2, const float* __restrict__ be_n2,
    u16* __restrict__ tx, u16* __restrict__ txln) {
  const int row = blockIdx.x, t = threadIdx.x;
  __shared__ float red[256];
  float a0 = rep_raw[(size_t)row * DD2 + t];
  float a1 = rep_raw[(size_t)row * DD2 + 256 + t];
  red[t] = a0 + a1; __syncthreads();
  for (int s = 128; s > 0; s >>= 1) { if (t < s) red[t] += red[t + s]; __syncthreads(); }
  float mean = red[0] * (1.0f / DD2); __syncthreads();
  float d0 = a0 - mean, d1 = a1 - mean;
  red[t] = d0 * d0 + d1 * d1; __syncthreads();
  for (int s = 128; s > 0; s >>= 1) { if (t < s) red[t] += red[t + s]; __syncthreads(); }
  float inv = rsqrtf(red[0] * (1.0f / DD2) + 1e-5f);
  __syncthreads();
  float r0 = d0 * inv * g_an[t] + be_an[t];
  float r1 = d1 * inv * g_an[256 + t] + be_an[256 + t];
  float t0 = x1e[(size_t)row * DD + t] + r0;
  float t1 = x2[(size_t)row * DD + t] + r1;
  tx[(size_t)row * DD2 + t] = f2bf(t0);
  tx[(size_t)row * DD2 + 256 + t] = f2bf(t1);
  // second LN over (t0,t1)
  red[t] = t0 + t1; __syncthreads();
  for (int s = 128; s > 0; s >>= 1) { if (t < s) red[t] += red[t + s]; __syncthreads(); }
  mean = red[0] * (1.0f / DD2); __syncthreads();
  d0 = t0 - mean; d1 = t1 - mean;
  red[t] = d0 * d0 + d1 * d1; __syncthreads();
  for (int s = 128; s > 0; s >>= 1) { if (t < s) red[t] += red[t + s]; __syncthreads(); }
  inv = rsqrtf(red[0] * (1.0f / DD2) + 1e-5f);
  txln[(size_t)row * DD2 + t] = f2bf(d0 * inv * g_n2[t] + be_n2[t]);
  txln[(size_t)row * DD2 + 256 + t] = f2bf(d1 * inv * g_n2[256 + t] + be_n2[256 + t]);
}

// ------- c8a: dw-conv3d + skip + LN + GELU -> ax bf16 -------
__global__ __launch_bounds__(256) void c8a_conv(
    const u16* __restrict__ h, const float* __restrict__ w_dw,
    const float* __restrict__ b_dw, const float* __restrict__ g,
    const float* __restrict__ be, u16* __restrict__ ax) {
  const int row = blockIdx.x, t = threadIdx.x;
  const int b = row >> 12, n = row & (NN - 1);
  const int z = n >> 8, y = (n >> 4) & 15, x = n & 15;
  __shared__ float red[256];
  float acc[4];
#pragma unroll
  for (int j = 0; j < 4; ++j) acc[j] = b_dw[t + 256 * j];
  const size_t hb = (size_t)b * NN * CC2;
  for (int dz = -1; dz <= 1; ++dz) {
    int zz = z + dz; if (zz < 0 || zz > 15) continue;
    for (int dy = -1; dy <= 1; ++dy) {
      int yy = y + dy; if (yy < 0 || yy > 15) continue;
      for (int dx = -1; dx <= 1; ++dx) {
        int xx = x + dx; if (xx < 0 || xx > 15) continue;
        int np = (zz << 8) | (yy << 4) | xx;
        int widx = (dz + 1) * 9 + (dy + 1) * 3 + (dx + 1);
        const u16* hp = h + hb + (size_t)np * CC2;
#pragma unroll
        for (int j = 0; j < 4; ++j)
          acc[j] += bf2f(hp[t + 256 * j]) * w_dw[(t + 256 * j) * 27 + widx];
      }
    }
  }
  float v[4];
  float ssum = 0.f;
#pragma unroll
  for (int j = 0; j < 4; ++j) {
    v[j] = acc[j] + bf2f(h[hb + (size_t)n * CC2 + t + 256 * j]);
    ssum += v[j];
  }
  red[t] = ssum; __syncthreads();
  for (int s = 128; s > 0; s >>= 1) { if (t < s) red[t] += red[t + s]; __syncthreads(); }
  float mean = red[0] * (1.0f / CC2); __syncthreads();
  float sq = 0.f;
#pragma unroll
  for (int j = 0; j < 4; ++j) { v[j] -= mean; sq += v[j] * v[j]; }
  red[t] = sq; __syncthreads();
  for (int s = 128; s > 0; s >>= 1) { if (t < s) red[t] += red[t + s]; __syncthreads(); }
  float inv = rsqrtf(red[0] * (1.0f / CC2) + 1e-5f);
#pragma unroll
  for (int j = 0; j < 4; ++j) {
    float u = v[j] * inv * g[t + 256 * j] + be[t + 256 * j];
    ax[(size_t)row * CC2 + t + 256 * j] =
        f2bf(0.5f * u * (1.0f + erff(u * 0.70710678118654752f)));
  }
}

// ------- l4: out = LN128 over ye groups -------
__global__ __launch_bounds__(256) void l4_out(
    const float* __restrict__ ye, const float* __restrict__ g_up,
    const float* __restrict__ be_up, float* __restrict__ out) {
  const int row = blockIdx.x, t = threadIdx.x;
  float4 v = reinterpret_cast<const float4*>(ye)[(size_t)row * 256 + t];
  float s1 = v.x + v.y + v.z + v.w;
  float s2 = v.x * v.x + v.y * v.y + v.z * v.z + v.w * v.w;
  for (int m = 1; m < 32; m <<= 1) {
    s1 += __shfl_xor(s1, m, 32);
    s2 += __shfl_xor(s2, m, 32);
  }
  float mean = s1 * (1.0f / 128.0f);
  float var = s2 * (1.0f / 128.0f) - mean * mean;
  float inv = rsqrtf(var + 1e-5f);
  int c0 = (t & 31) * 4;
  size_t ob = ((size_t)row * 8 + (t >> 5)) * 128 + c0;
  out[ob]     = (v.x - mean) * inv * g_up[c0]     + be_up[c0];
  out[ob + 1] = (v.y - mean) * inv * g_up[c0 + 1] + be_up[c0 + 1];
  out[ob + 2] = (v.z - mean) * inv * g_up[c0 + 2] + be_up[c0 + 2];
  out[ob + 3] = (v.w - mean) * inv * g_up[c0 + 3] + be_up[c0 + 3];
}

extern "C" void kernel_launch(void* const* d_in, const int* in_sizes, int n_in,
                              void* d_out, int out_size, void* d_ws, size_t ws_size,
                              hipStream_t stream) {
  const float* x1    = (const float*)d_in[0];
  const float* x2    = (const float*)d_in[1];
  const float* w_x1  = (const float*)d_in[2];
  const float* b_x1  = (const float*)d_in[3];
  const float* g_n1  = (const float*)d_in[4];
  const float* be_n1 = (const float*)d_in[5];
  const float* w_rep = (const float*)d_in[6];
  const float* b_rep = (const float*)d_in[7];
  const float* g_an  = (const float*)d_in[8];
  const float* be_an = (const float*)d_in[9];
  const float* g_n2  = (const float*)d_in[10];
  const float* be_n2 = (const float*)d_in[11];
  const float* w_fc1 = (const float*)d_in[12];
  const float* b_fc1 = (const float*)d_in[13];
  const float* w_dw  = (const float*)d_in[14];
  const float* b_dw  = (const float*)d_in[15];
  const float* g_m1  = (const float*)d_in[16];
  const float* be_m1 = (const float*)d_in[17];
  const float* w_fc2 = (const float*)d_in[18];
  const float* b_fc2 = (const float*)d_in[19];
  const float* w_cat = (const float*)d_in[20];
  const float* b_cat = (const float*)d_in[21];
  const float* w_exp = (const float*)d_in[22];
  const float* g_up  = (const float*)d_in[23];
  const float* be_up = (const float*)d_in[24];

  char* ws = (char*)d_ws;
  float* out = (float*)d_out;

  u16*   x1b     = (u16*)(ws + 0);
  float* x1e     = (float*)(ws + 8 * MB);
  u16*   n1      = (u16*)(ws + 24 * MB);
  float* n2      = (float*)(ws + 32 * MB);
  float* kmax    = (float*)(ws + 48 * MB);
  float* ksum    = kmax + 1024;
  float* ctx     = kmax + 2048;
  float* rep_raw = (float*)(ws + 49 * MB);
  u16*   tx      = (u16*)(ws + 81 * MB);
  u16*   txln    = (u16*)(ws + 97 * MB);
  u16*   hbuf    = (u16*)(ws + 113 * MB);
  u16*   attT    = (u16*)(ws + 0);
  u16*   ax      = (u16*)(ws + 49 * MB);
  u16*   mx      = (u16*)(ws + 8 * MB);
  u16*   ybuf    = (u16*)(ws + 0);
  float* ye      = (float*)(ws + 49 * MB);
  u16*   w_x1t   = (u16*)(ws + 145 * MB);
  u16*   w_rept  = w_x1t + 256 * 256;
  u16*   w_fc1t  = w_rept + 512 * 256;
  u16*   w_fc2t  = w_fc1t + 1024 * 512;
  u16*   w_catt  = w_fc2t + 512 * 1024;
  u16*   w_expt  = w_catt + 256 * 512;

  // weight transposes ([K][N] -> bf16 [N][K])
  wconv_t<<<(256 * 256 + 255) / 256, 256, 0, stream>>>(w_x1, w_x1t, 256, 256);
  wconv_t<<<(256 * 512 + 255) / 256, 256, 0, stream>>>(w_rep, w_rept, 256, 512);
  wconv_t<<<(512 * 1024 + 255) / 256, 256, 0, stream>>>(w_fc1, w_fc1t, 512, 1024);
  wconv_t<<<(1024 * 512 + 255) / 256, 256, 0, stream>>>(w_fc2, w_fc2t, 1024, 512);
  wconv_t<<<(512 * 256 + 255) / 256, 256, 0, stream>>>(w_cat, w_catt, 512, 256);
  wconv_t<<<(256 * 1024 + 255) / 256, 256, 0, stream>>>(w_exp, w_expt, 256, 1024);

  cast8<<<(ROWS * DD / 8 + 255) / 256, 256, 0, stream>>>(x1, x1b, ROWS * DD / 8);

  // g1: x1e = x1b @ w_x1 + b (fp32 out)
  gemm_mfma<256, 0><<<(ROWS / 128) * 2, 256, 0, stream>>>(x1b, w_x1t, b_x1, nullptr, x1e, 2);
  // l1/l2
  ln256<true><<<ROWS, 256, 0, stream>>>(x1e, g_n1, be_n1, n1);
  ln256<false><<<ROWS, 256, 0, stream>>>(x2, g_n1, be_n1, n2);
  // attention
  k3_kstats<<<BB * DD, 256, 0, stream>>>(n2, kmax, ksum);
  k4_ctx<<<BB * DD, 256, 0, stream>>>(n1, n2, kmax, ksum, ctx);
  k5_attT<<<ROWS, 256, 0, stream>>>(n2, ctx, attT);
  // g2: rep_raw = attT @ w_rep + b (fp32 out)
  gemm_mfma<256, 0><<<(ROWS / 128) * 4, 256, 0, stream>>>(attT, w_rept, b_rep, nullptr, rep_raw, 4);
  l3_reptx<<<ROWS, 256, 0, stream>>>(rep_raw, x1e, x2, g_an, be_an, g_n2, be_n2, tx, txln);
  // g3: h = txln @ w_fc1 + b (bf16 out)
  gemm_mfma<512, 1><<<(ROWS / 128) * 8, 256, 0, stream>>>(txln, w_fc1t, b_fc1, nullptr, hbuf, 8);
  c8a_conv<<<ROWS, 256, 0, stream>>>(hbuf, w_dw, b_dw, g_m1, be_m1, ax);
  // g4: mx = tx + ax @ w_fc2 + b (bf16 out, bf16 residual)
  gemm_mfma<1024, 2><<<(ROWS / 128) * 4, 256, 0, stream>>>(ax, w_fc2t, b_fc2, tx, mx, 4);
  // g5: y = mx @ w_cat + b (bf16 out)
  gemm_mfma<512, 1><<<(ROWS / 128) * 2, 256, 0, stream>>>(mx, w_catt, b_cat, nullptr, ybuf, 2);
  // g6: ye = y @ w_exp (fp32 out, no bias)
  gemm_mfma<256, 0><<<(ROWS / 128) * 8, 256, 0, stream>>>(ybuf, w_expt, nullptr, nullptr, ye, 8);
  l4_out<<<ROWS, 256, 0, stream>>>(ye, g_up, be_up, out);
}

// Round 3
// 489.513 us; speedup vs baseline: 9.6748x; 3.1036x over previous
//
#include <hip/hip_runtime.h>
#include <math.h>

using u16 = unsigned short;
typedef __bf16 bf16x8 __attribute__((ext_vector_type(8)));
typedef float f32x4 __attribute__((ext_vector_type(4)));

#define BB 4
#define NN 4096
#define DD 256
#define DD2 512
#define CC2 1024
static constexpr int ROWS = BB * NN;  // 16384
static constexpr size_t MB = 1024 * 1024;

__device__ __forceinline__ u16 f2bf(float f) {
  union { float f; unsigned u; } v; v.f = f;
  unsigned r = v.u + 0x7fffu + ((v.u >> 16) & 1u);
  return (u16)(r >> 16);
}
__device__ __forceinline__ float bf2f(u16 u) {
  union { unsigned u; float f; } v; v.u = ((unsigned)u) << 16;
  return v.f;
}
__device__ __forceinline__ float u2f(unsigned x) {
  union { unsigned u; float f; } v; v.u = x; return v.f;
}

// ---------------- weight transpose + cast: out[n*K+k] = in[k*N+n] ----------------
__global__ __launch_bounds__(256) void wconv_t(const float* __restrict__ in,
                                               u16* __restrict__ out,
                                               int K, int N) {
  int i = blockIdx.x * 256 + threadIdx.x;
  if (i >= K * N) return;
  int n = i / K, k = i - n * K;
  out[i] = f2bf(in[(size_t)k * N + n]);
}

// ---------------- depthwise weight transpose: [1024][27] -> [27][1024] fp32 ----------------
__global__ __launch_bounds__(256) void wdw_t(const float* __restrict__ in,
                                             float* __restrict__ out) {
  int i = blockIdx.x * 256 + threadIdx.x;
  if (i >= 27 * CC2) return;
  int widx = i >> 10, c = i & 1023;
  out[i] = in[c * 27 + widx];
}

// ---------------- cast fp32 -> bf16, 8 elems/thread ----------------
__global__ __launch_bounds__(256) void cast8(const float* __restrict__ in,
                                             u16* __restrict__ out, int n8) {
  int i = blockIdx.x * 256 + threadIdx.x;
  if (i >= n8) return;
  float4 a = reinterpret_cast<const float4*>(in)[i * 2];
  float4 b = reinterpret_cast<const float4*>(in)[i * 2 + 1];
  u16 o[8] = {f2bf(a.x), f2bf(a.y), f2bf(a.z), f2bf(a.w),
              f2bf(b.x), f2bf(b.y), f2bf(b.z), f2bf(b.w)};
  reinterpret_cast<uint4*>(out)[i] = *reinterpret_cast<uint4*>(o);
}

// ---------------- generic 128x128-tile MFMA GEMM ----------------
// A [M][K] bf16, Bt [N][K] bf16, C row-major [M][Ncols]
// EPI: 0 = f32 out, 1 = bf16 out, 2 = bf16 out with bf16 residual add
template <int K, int EPI>
__global__ __launch_bounds__(256, 2) void gemm_mfma(
    const u16* __restrict__ A, const u16* __restrict__ Bt,
    const float* __restrict__ bias, const u16* __restrict__ resid,
    void* __restrict__ Cout, int nTilesN) {
  const int t = threadIdx.x;
  const int m0 = (blockIdx.x / nTilesN) * 128;
  const int n0 = (blockIdx.x % nTilesN) * 128;
  const int Ncols = nTilesN * 128;
  const int lane = t & 63, wid = t >> 6;
  const int wr = wid >> 1, wc = wid & 1;
  const int lrow = lane & 15, kgrp = lane >> 4;

  __shared__ u16 ldsA[2][128 * 32];
  __shared__ u16 ldsB[2][128 * 32];

  int srow[2], sslot[2];
#pragma unroll
  for (int c = 0; c < 2; ++c) {
    int idx = c * 256 + t;
    srow[c] = idx >> 2;
    sslot[c] = (idx & 3) ^ ((srow[c] >> 1) & 3);
  }

  int offA[4], offB[4];
#pragma unroll
  for (int m = 0; m < 4; ++m) {
    int r = wr * 64 + m * 16 + lrow;
    offA[m] = r * 32 + ((kgrp ^ ((r >> 1) & 3)) * 8);
  }
#pragma unroll
  for (int n = 0; n < 4; ++n) {
    int r = wc * 64 + n * 16 + lrow;
    offB[n] = r * 32 + ((kgrp ^ ((r >> 1) & 3)) * 8);
  }

  f32x4 acc[4][4];
#pragma unroll
  for (int m = 0; m < 4; ++m)
#pragma unroll
    for (int n = 0; n < 4; ++n) acc[m][n] = f32x4{0.f, 0.f, 0.f, 0.f};

  uint4 ra[2], rb[2];
#pragma unroll
  for (int c = 0; c < 2; ++c) {
    ra[c] = *(const uint4*)(A + (size_t)(m0 + srow[c]) * K + sslot[c] * 8);
    rb[c] = *(const uint4*)(Bt + (size_t)(n0 + srow[c]) * K + sslot[c] * 8);
  }
#pragma unroll
  for (int c = 0; c < 2; ++c) {
    int idx = c * 256 + t;
    *(uint4*)&ldsA[0][idx * 8] = ra[c];
    *(uint4*)&ldsB[0][idx * 8] = rb[c];
  }
  __syncthreads();

  const int nt = K / 32;
  for (int tt = 0; tt < nt; ++tt) {
    const int cur = tt & 1;
    if (tt + 1 < nt) {
      const int kc = (tt + 1) * 32;
#pragma unroll
      for (int c = 0; c < 2; ++c) {
        ra[c] = *(const uint4*)(A + (size_t)(m0 + srow[c]) * K + kc + sslot[c] * 8);
        rb[c] = *(const uint4*)(Bt + (size_t)(n0 + srow[c]) * K + kc + sslot[c] * 8);
      }
    }
    bf16x8 af[4], bf[4];
#pragma unroll
    for (int m = 0; m < 4; ++m) af[m] = *(const bf16x8*)&ldsA[cur][offA[m]];
#pragma unroll
    for (int n = 0; n < 4; ++n) bf[n] = *(const bf16x8*)&ldsB[cur][offB[n]];
#pragma unroll
    for (int m = 0; m < 4; ++m)
#pragma unroll
      for (int n = 0; n < 4; ++n)
        acc[m][n] = __builtin_amdgcn_mfma_f32_16x16x32_bf16(af[m], bf[n], acc[m][n], 0, 0, 0);
    if (tt + 1 < nt) {
#pragma unroll
      for (int c = 0; c < 2; ++c) {
        int idx = c * 256 + t;
        *(uint4*)&ldsA[cur ^ 1][idx * 8] = ra[c];
        *(uint4*)&ldsB[cur ^ 1][idx * 8] = rb[c];
      }
    }
    __syncthreads();
  }

  float bcol[4];
#pragma unroll
  for (int n = 0; n < 4; ++n) {
    int col = n0 + wc * 64 + n * 16 + (lane & 15);
    bcol[n] = bias ? bias[col] : 0.f;
  }
#pragma unroll
  for (int m = 0; m < 4; ++m) {
    const int r0 = m0 + wr * 64 + m * 16 + kgrp * 4;
#pragma unroll
    for (int n = 0; n < 4; ++n) {
      const int col = n0 + wc * 64 + n * 16 + (lane & 15);
#pragma unroll
      for (int j = 0; j < 4; ++j) {
        float v = acc[m][n][j] + bcol[n];
        size_t idx = (size_t)(r0 + j) * Ncols + col;
        if (EPI == 0) {
          ((float*)Cout)[idx] = v;
        } else if (EPI == 1) {
          ((u16*)Cout)[idx] = f2bf(v);
        } else {
          v += bf2f(resid[idx]);
          ((u16*)Cout)[idx] = f2bf(v);
        }
      }
    }
  }
}

// ---------------- per-row LN over 256, optional bf16 out ----------------
template <bool OBF>
__global__ __launch_bounds__(256) void ln256(const float* __restrict__ in,
                                             const float* __restrict__ g,
                                             const float* __restrict__ be,
                                             void* __restrict__ out) {
  const int row = blockIdx.x, t = threadIdx.x;
  __shared__ float red[256];
  float v = in[(size_t)row * DD + t];
  red[t] = v; __syncthreads();
  for (int s = 128; s > 0; s >>= 1) { if (t < s) red[t] += red[t + s]; __syncthreads(); }
  float mean = red[0] * (1.0f / DD); __syncthreads();
  float dv = v - mean;
  red[t] = dv * dv; __syncthreads();
  for (int s = 128; s > 0; s >>= 1) { if (t < s) red[t] += red[t + s]; __syncthreads(); }
  float inv = rsqrtf(red[0] * (1.0f / DD) + 1e-5f);
  float r = dv * inv * g[t] + be[t];
  if (OBF) ((u16*)out)[(size_t)row * DD + t] = f2bf(r);
  else ((float*)out)[(size_t)row * DD + t] = r;
}

// ---------------- k3: per-(b,d) column softmax stats over tokens ----------------
__global__ __launch_bounds__(256) void k3_kstats(
    const float* __restrict__ n2, float* __restrict__ kmax,
    float* __restrict__ ksum) {
  const int b = blockIdx.x >> 8, d = blockIdx.x & 255, t = threadIdx.x;
  float vals[16];
  float mx = -1e30f;
  for (int i = 0; i < 16; ++i) {
    float v = n2[((size_t)b * NN + (i * 256 + t)) * DD + d];
    vals[i] = v; mx = fmaxf(mx, v);
  }
  __shared__ float red[256];
  red[t] = mx; __syncthreads();
  for (int s = 128; s > 0; s >>= 1) { if (t < s) red[t] = fmaxf(red[t], red[t + s]); __syncthreads(); }
  mx = red[0]; __syncthreads();
  float sm = 0.f;
  for (int i = 0; i < 16; ++i) sm += expf(vals[i] - mx);
  red[t] = sm; __syncthreads();
  for (int s = 128; s > 0; s >>= 1) { if (t < s) red[t] += red[t + s]; __syncthreads(); }
  if (t == 0) { kmax[blockIdx.x] = mx; ksum[blockIdx.x] = red[0]; }
}

// ---------------- k4: ctx[b,h,k,v] = sum_n softmaxK(n2) * n1 ----------------
__global__ __launch_bounds__(256) void k4_ctx(
    const u16* __restrict__ n1, const float* __restrict__ n2,
    const float* __restrict__ kmax, const float* __restrict__ ksum,
    float* __restrict__ ctx) {
  const int bx = blockIdx.x;
  const int b = bx >> 8, h = (bx >> 5) & 7, kk = bx & 31;
  const int t = threadIdx.x;
  const int dk = h * 32 + kk;
  const float mx = kmax[b * DD + dk];
  const float inv = 1.0f / ksum[b * DD + dk];
  float acc[32];
#pragma unroll
  for (int v = 0; v < 32; ++v) acc[v] = 0.f;
  for (int i = 0; i < 16; ++i) {
    const int n = i * 256 + t;
    const size_t base = ((size_t)b * NN + n) * DD;
    const float kv = expf(n2[base + dk] - mx) * inv;
    const u16* v1 = n1 + base + h * 32;
#pragma unroll
    for (int q = 0; q < 4; ++q) {
      uint4 u = *(const uint4*)(v1 + q * 8);
      unsigned w[4] = {u.x, u.y, u.z, u.w};
#pragma unroll
      for (int p = 0; p < 4; ++p) {
        acc[q * 8 + p * 2]     += kv * u2f(w[p] << 16);
        acc[q * 8 + p * 2 + 1] += kv * u2f(w[p] & 0xffff0000u);
      }
    }
  }
  __shared__ float sm[256 * 32];
#pragma unroll
  for (int v = 0; v < 32; ++v) sm[t * 32 + v] = acc[v];
  __syncthreads();
  for (int s = 128; s > 0; s >>= 1) {
    if (t < s) {
#pragma unroll
      for (int v = 0; v < 32; ++v) sm[t * 32 + v] += sm[(t + s) * 32 + v];
    }
    __syncthreads();
  }
  if (t < 32) ctx[(((size_t)b * 8 + h) * 32 + kk) * 32 + t] = sm[t];
}

// ---------------- k5: attT[b,n,d] = sum_k ctx * softmaxQ ----------------
__global__ __launch_bounds__(256) void k5_attT(
    const float* __restrict__ n2, const float* __restrict__ ctx,
    u16* __restrict__ attT) {
  const int row = blockIdx.x, t = threadIdx.x;
  const int b = row >> 12;
  const int h = t >> 5, v = t & 31;
  __shared__ float nr[DD];
  __shared__ float q[DD];
  nr[t] = n2[(size_t)row * DD + t];
  __syncthreads();
  float mx = -1e30f;
  for (int c = 0; c < 32; ++c) mx = fmaxf(mx, nr[h * 32 + c]);
  float sm = 0.f;
  for (int c = 0; c < 32; ++c) sm += expf(nr[h * 32 + c] - mx);
  q[t] = expf(nr[t] - mx) / sm;
  __syncthreads();
  const float* cb = ctx + ((size_t)(b * 8 + h) * 32) * 32 + v;
  float acc = 0.f;
#pragma unroll
  for (int k = 0; k < 32; ++k) acc += cb[k * 32] * q[h * 32 + k];
  attT[(size_t)row * DD + t] = f2bf(acc);
}

// ------- l3: rep = LN(rep_raw); tx = concat(x1e,x2)+rep (bf16); txln = LN(tx) bf16 -------
__global__ __launch_bounds__(256) void l3_reptx(
    const float* __restrict__ rep_raw, const float* __restrict__ x1e,
    const float* __restrict__ x2,
    const float* __restrict__ g_an, const float* __restrict__ be_an,
    const float* __restrict__ g_n2, const float* __restrict__ be_n2,
    u16* __restrict__ tx, u16* __restrict__ txln) {
  const int row = blockIdx.x, t = threadIdx.x;
  __shared__ float red[256];
  float a0 = rep_raw[(size_t)row * DD2 + t];
  float a1 = rep_raw[(size_t)row * DD2 + 256 + t];
  red[t] = a0 + a1; __syncthreads();
  for (int s = 128; s > 0; s >>= 1) { if (t < s) red[t] += red[t + s]; __syncthreads(); }
  float mean = red[0] * (1.0f / DD2); __syncthreads();
  float d0 = a0 - mean, d1 = a1 - mean;
  red[t] = d0 * d0 + d1 * d1; __syncthreads();
  for (int s = 128; s > 0; s >>= 1) { if (t < s) red[t] += red[t + s]; __syncthreads(); }
  float inv = rsqrtf(red[0] * (1.0f / DD2) + 1e-5f);
  __syncthreads();
  float r0 = d0 * inv * g_an[t] + be_an[t];
  float r1 = d1 * inv * g_an[256 + t] + be_an[256 + t];
  float t0 = x1e[(size_t)row * DD + t] + r0;
  float t1 = x2[(size_t)row * DD + t] + r1;
  tx[(size_t)row * DD2 + t] = f2bf(t0);
  tx[(size_t)row * DD2 + 256 + t] = f2bf(t1);
  red[t] = t0 + t1; __syncthreads();
  for (int s = 128; s > 0; s >>= 1) { if (t < s) red[t] += red[t + s]; __syncthreads(); }
  mean = red[0] * (1.0f / DD2); __syncthreads();
  d0 = t0 - mean; d1 = t1 - mean;
  red[t] = d0 * d0 + d1 * d1; __syncthreads();
  for (int s = 128; s > 0; s >>= 1) { if (t < s) red[t] += red[t + s]; __syncthreads(); }
  inv = rsqrtf(red[0] * (1.0f / DD2) + 1e-5f);
  txln[(size_t)row * DD2 + t] = f2bf(d0 * inv * g_n2[t] + be_n2[t]);
  txln[(size_t)row * DD2 + 256 + t] = f2bf(d1 * inv * g_n2[256 + t] + be_n2[256 + t]);
}

// ------- c8a: dw-conv3d + skip + LN + GELU -> ax bf16 (coalesced, vectorized) -------
// thread t owns channels [4t .. 4t+3]; w_dwt is [27][1024] fp32
__global__ __launch_bounds__(256) void c8a_conv(
    const u16* __restrict__ h, const float* __restrict__ w_dwt,
    const float* __restrict__ b_dw, const float* __restrict__ g,
    const float* __restrict__ be, u16* __restrict__ ax) {
  const int row = blockIdx.x, t = threadIdx.x;
  const int b = row >> 12, n = row & (NN - 1);
  const int z = n >> 8, y = (n >> 4) & 15, x = n & 15;
  const int c0 = t * 4;
  __shared__ float red[256];
  float4 bv = *(const float4*)(b_dw + c0);
  float acc[4] = {bv.x, bv.y, bv.z, bv.w};
  const size_t hb = (size_t)b * NN * CC2;
  for (int dz = -1; dz <= 1; ++dz) {
    int zz = z + dz; if (zz < 0 || zz > 15) continue;
    for (int dy = -1; dy <= 1; ++dy) {
      int yy = y + dy; if (yy < 0 || yy > 15) continue;
      for (int dx = -1; dx <= 1; ++dx) {
        int xx = x + dx; if (xx < 0 || xx > 15) continue;
        int np = (zz << 8) | (yy << 4) | xx;
        int widx = (dz + 1) * 9 + (dy + 1) * 3 + (dx + 1);
        float4 w4 = *(const float4*)(w_dwt + widx * CC2 + c0);
        uint2 hv = *(const uint2*)(h + hb + (size_t)np * CC2 + c0);
        acc[0] += u2f(hv.x << 16) * w4.x;
        acc[1] += u2f(hv.x & 0xffff0000u) * w4.y;
        acc[2] += u2f(hv.y << 16) * w4.z;
        acc[3] += u2f(hv.y & 0xffff0000u) * w4.w;
      }
    }
  }
  uint2 hs = *(const uint2*)(h + hb + (size_t)n * CC2 + c0);
  float v[4];
  v[0] = acc[0] + u2f(hs.x << 16);
  v[1] = acc[1] + u2f(hs.x & 0xffff0000u);
  v[2] = acc[2] + u2f(hs.y << 16);
  v[3] = acc[3] + u2f(hs.y & 0xffff0000u);
  float ssum = v[0] + v[1] + v[2] + v[3];
  red[t] = ssum; __syncthreads();
  for (int s = 128; s > 0; s >>= 1) { if (t < s) red[t] += red[t + s]; __syncthreads(); }
  float mean = red[0] * (1.0f / CC2); __syncthreads();
  float sq = 0.f;
#pragma unroll
  for (int j = 0; j < 4; ++j) { v[j] -= mean; sq += v[j] * v[j]; }
  red[t] = sq; __syncthreads();
  for (int s = 128; s > 0; s >>= 1) { if (t < s) red[t] += red[t + s]; __syncthreads(); }
  float inv = rsqrtf(red[0] * (1.0f / CC2) + 1e-5f);
  float4 gg = *(const float4*)(g + c0);
  float4 bb = *(const float4*)(be + c0);
  float gv[4] = {gg.x, gg.y, gg.z, gg.w};
  float bvv[4] = {bb.x, bb.y, bb.z, bb.w};
  u16 o[4];
#pragma unroll
  for (int j = 0; j < 4; ++j) {
    float u = v[j] * inv * gv[j] + bvv[j];
    o[j] = f2bf(0.5f * u * (1.0f + erff(u * 0.70710678118654752f)));
  }
  *(uint2*)(ax + (size_t)row * CC2 + c0) = *(uint2*)o;
}

// ------- l4: out = LN128 over ye groups -------
__global__ __launch_bounds__(256) void l4_out(
    const float* __restrict__ ye, const float* __restrict__ g_up,
    const float* __restrict__ be_up, float* __restrict__ out) {
  const int row = blockIdx.x, t = threadIdx.x;
  float4 v = reinterpret_cast<const float4*>(ye)[(size_t)row * 256 + t];
  float s1 = v.x + v.y + v.z + v.w;
  float s2 = v.x * v.x + v.y * v.y + v.z * v.z + v.w * v.w;
  for (int m = 1; m < 32; m <<= 1) {
    s1 += __shfl_xor(s1, m, 32);
    s2 += __shfl_xor(s2, m, 32);
  }
  float mean = s1 * (1.0f / 128.0f);
  float var = s2 * (1.0f / 128.0f) - mean * mean;
  float inv = rsqrtf(var + 1e-5f);
  int c0 = (t & 31) * 4;
  size_t ob = ((size_t)row * 8 + (t >> 5)) * 128 + c0;
  out[ob]     = (v.x - mean) * inv * g_up[c0]     + be_up[c0];
  out[ob + 1] = (v.y - mean) * inv * g_up[c0 + 1] + be_up[c0 + 1];
  out[ob + 2] = (v.z - mean) * inv * g_up[c0 + 2] + be_up[c0 + 2];
  out[ob + 3] = (v.w - mean) * inv * g_up[c0 + 3] + be_up[c0 + 3];
}

extern "C" void kernel_launch(void* const* d_in, const int* in_sizes, int n_in,
                              void* d_out, int out_size, void* d_ws, size_t ws_size,
                              hipStream_t stream) {
  const float* x1    = (const float*)d_in[0];
  const float* x2    = (const float*)d_in[1];
  const float* w_x1  = (const float*)d_in[2];
  const float* b_x1  = (const float*)d_in[3];
  const float* g_n1  = (const float*)d_in[4];
  const float* be_n1 = (const float*)d_in[5];
  const float* w_rep = (const float*)d_in[6];
  const float* b_rep = (const float*)d_in[7];
  const float* g_an  = (const float*)d_in[8];
  const float* be_an = (const float*)d_in[9];
  const float* g_n2  = (const float*)d_in[10];
  const float* be_n2 = (const float*)d_in[11];
  const float* w_fc1 = (const float*)d_in[12];
  const float* b_fc1 = (const float*)d_in[13];
  const float* w_dw  = (const float*)d_in[14];
  const float* b_dw  = (const float*)d_in[15];
  const float* g_m1  = (const float*)d_in[16];
  const float* be_m1 = (const float*)d_in[17];
  const float* w_fc2 = (const float*)d_in[18];
  const float* b_fc2 = (const float*)d_in[19];
  const float* w_cat = (const float*)d_in[20];
  const float* b_cat = (const float*)d_in[21];
  const float* w_exp = (const float*)d_in[22];
  const float* g_up  = (const float*)d_in[23];
  const float* be_up = (const float*)d_in[24];

  char* ws = (char*)d_ws;
  float* out = (float*)d_out;

  u16*   x1b     = (u16*)(ws + 0);
  float* x1e     = (float*)(ws + 8 * MB);
  u16*   n1      = (u16*)(ws + 24 * MB);
  float* n2      = (float*)(ws + 32 * MB);
  float* kmax    = (float*)(ws + 48 * MB);
  float* ksum    = kmax + 1024;
  float* ctx     = kmax + 2048;
  float* rep_raw = (float*)(ws + 49 * MB);
  u16*   tx      = (u16*)(ws + 81 * MB);
  u16*   txln    = (u16*)(ws + 97 * MB);
  u16*   hbuf    = (u16*)(ws + 113 * MB);
  u16*   attT    = (u16*)(ws + 0);
  u16*   ax      = (u16*)(ws + 49 * MB);
  u16*   mx      = (u16*)(ws + 8 * MB);
  u16*   ybuf    = (u16*)(ws + 0);
  float* ye      = (float*)(ws + 49 * MB);
  u16*   w_x1t   = (u16*)(ws + 145 * MB);
  u16*   w_rept  = w_x1t + 256 * 256;
  u16*   w_fc1t  = w_rept + 512 * 256;
  u16*   w_fc2t  = w_fc1t + 1024 * 512;
  u16*   w_catt  = w_fc2t + 512 * 1024;
  u16*   w_expt  = w_catt + 256 * 512;
  float* w_dwt   = (float*)(ws + 149 * MB);  // 27*1024 fp32

  wconv_t<<<(256 * 256 + 255) / 256, 256, 0, stream>>>(w_x1, w_x1t, 256, 256);
  wconv_t<<<(256 * 512 + 255) / 256, 256, 0, stream>>>(w_rep, w_rept, 256, 512);
  wconv_t<<<(512 * 1024 + 255) / 256, 256, 0, stream>>>(w_fc1, w_fc1t, 512, 1024);
  wconv_t<<<(1024 * 512 + 255) / 256, 256, 0, stream>>>(w_fc2, w_fc2t, 1024, 512);
  wconv_t<<<(512 * 256 + 255) / 256, 256, 0, stream>>>(w_cat, w_catt, 512, 256);
  wconv_t<<<(256 * 1024 + 255) / 256, 256, 0, stream>>>(w_exp, w_expt, 256, 1024);
  wdw_t<<<(27 * CC2 + 255) / 256, 256, 0, stream>>>(w_dw, w_dwt);

  cast8<<<(ROWS * DD / 8 + 255) / 256, 256, 0, stream>>>(x1, x1b, ROWS * DD / 8);

  gemm_mfma<256, 0><<<(ROWS / 128) * 2, 256, 0, stream>>>(x1b, w_x1t, b_x1, nullptr, x1e, 2);
  ln256<true><<<ROWS, 256, 0, stream>>>(x1e, g_n1, be_n1, n1);
  ln256<false><<<ROWS, 256, 0, stream>>>(x2, g_n1, be_n1, n2);
  k3_kstats<<<BB * DD, 256, 0, stream>>>(n2, kmax, ksum);
  k4_ctx<<<BB * DD, 256, 0, stream>>>(n1, n2, kmax, ksum, ctx);
  k5_attT<<<ROWS, 256, 0, stream>>>(n2, ctx, attT);
  gemm_mfma<256, 0><<<(ROWS / 128) * 4, 256, 0, stream>>>(attT, w_rept, b_rep, nullptr, rep_raw, 4);
  l3_reptx<<<ROWS, 256, 0, stream>>>(rep_raw, x1e, x2, g_an, be_an, g_n2, be_n2, tx, txln);
  gemm_mfma<512, 1><<<(ROWS / 128) * 8, 256, 0, stream>>>(txln, w_fc1t, b_fc1, nullptr, hbuf, 8);
  c8a_conv<<<ROWS, 256, 0, stream>>>(hbuf, w_dwt, b_dw, g_m1, be_m1, ax);
  gemm_mfma<1024, 2><<<(ROWS / 128) * 4, 256, 0, stream>>>(ax, w_fc2t, b_fc2, tx, mx, 4);
  gemm_mfma<512, 1><<<(ROWS / 128) * 2, 256, 0, stream>>>(mx, w_catt, b_cat, nullptr, ybuf, 2);
  gemm_mfma<256, 0><<<(ROWS / 128) * 8, 256, 0, stream>>>(ybuf, w_expt, nullptr, nullptr, ye, 8);
  l4_out<<<ROWS, 256, 0, stream>>>(ye, g_up, be_up, out);
}

// Round 4
// 390.667 us; speedup vs baseline: 12.1228x; 1.2530x over previous
//
#include <hip/hip_runtime.h>
#include <math.h>

using u16 = unsigned short;
typedef __bf16 bf16x8 __attribute__((ext_vector_type(8)));
typedef float f32x4 __attribute__((ext_vector_type(4)));

#define BB 4
#define NN 4096
#define DD 256
#define DD2 512
#define CC2 1024
static constexpr int ROWS = BB * NN;  // 16384
static constexpr size_t MB = 1024 * 1024;

__device__ __forceinline__ u16 f2bf(float f) {
  union { float f; unsigned u; } v; v.f = f;
  unsigned r = v.u + 0x7fffu + ((v.u >> 16) & 1u);
  return (u16)(r >> 16);
}
__device__ __forceinline__ float bf2f(u16 u) {
  union { unsigned u; float f; } v; v.u = ((unsigned)u) << 16;
  return v.f;
}
__device__ __forceinline__ float u2f(unsigned x) {
  union { unsigned u; float f; } v; v.u = x; return v.f;
}

// ---------------- weight transpose + cast: out[n*K+k] = in[k*N+n] ----------------
__global__ __launch_bounds__(256) void wconv_t(const float* __restrict__ in,
                                               u16* __restrict__ out,
                                               int K, int N) {
  int i = blockIdx.x * 256 + threadIdx.x;
  if (i >= K * N) return;
  int n = i / K, k = i - n * K;
  out[i] = f2bf(in[(size_t)k * N + n]);
}

// ---------------- depthwise weight transpose: [1024][27] -> [27][1024] fp32 ----------------
__global__ __launch_bounds__(256) void wdw_t(const float* __restrict__ in,
                                             float* __restrict__ out) {
  int i = blockIdx.x * 256 + threadIdx.x;
  if (i >= 27 * CC2) return;
  int widx = i >> 10, c = i & 1023;
  out[i] = in[c * 27 + widx];
}

// ---------------- cast fp32 -> bf16, 8 elems/thread ----------------
__global__ __launch_bounds__(256) void cast8(const float* __restrict__ in,
                                             u16* __restrict__ out, int n8) {
  int i = blockIdx.x * 256 + threadIdx.x;
  if (i >= n8) return;
  float4 a = reinterpret_cast<const float4*>(in)[i * 2];
  float4 b = reinterpret_cast<const float4*>(in)[i * 2 + 1];
  u16 o[8] = {f2bf(a.x), f2bf(a.y), f2bf(a.z), f2bf(a.w),
              f2bf(b.x), f2bf(b.y), f2bf(b.z), f2bf(b.w)};
  reinterpret_cast<uint4*>(out)[i] = *reinterpret_cast<uint4*>(o);
}

// ---------------- generic 128x128-tile MFMA GEMM ----------------
// A [M][K] bf16, Bt [N][K] bf16, C row-major [M][Ncols]
// EPI: 0 = f32 out, 1 = bf16 out, 2 = bf16 out + bf16 residual,
//      3 = f32 out with fused per-row LN over the 128-col tile (PatchExpand)
template <int K, int EPI>
__global__ __launch_bounds__(256, 2) void gemm_mfma(
    const u16* __restrict__ A, const u16* __restrict__ Bt,
    const float* __restrict__ bias, const u16* __restrict__ resid,
    void* __restrict__ Cout, int nTilesN,
    const float* __restrict__ gup, const float* __restrict__ beup) {
  const int t = threadIdx.x;
  const int m0 = (blockIdx.x / nTilesN) * 128;
  const int n0 = (blockIdx.x % nTilesN) * 128;
  const int Ncols = nTilesN * 128;
  const int lane = t & 63, wid = t >> 6;
  const int wr = wid >> 1, wc = wid & 1;
  const int lrow = lane & 15, kgrp = lane >> 4;

  __shared__ u16 ldsA[2][128 * 32];
  __shared__ u16 ldsB[2][128 * 32];

  int srow[2], sslot[2];
#pragma unroll
  for (int c = 0; c < 2; ++c) {
    int idx = c * 256 + t;
    srow[c] = idx >> 2;
    sslot[c] = (idx & 3) ^ ((srow[c] >> 1) & 3);
  }

  int offA[4], offB[4];
#pragma unroll
  for (int m = 0; m < 4; ++m) {
    int r = wr * 64 + m * 16 + lrow;
    offA[m] = r * 32 + ((kgrp ^ ((r >> 1) & 3)) * 8);
  }
#pragma unroll
  for (int n = 0; n < 4; ++n) {
    int r = wc * 64 + n * 16 + lrow;
    offB[n] = r * 32 + ((kgrp ^ ((r >> 1) & 3)) * 8);
  }

  f32x4 acc[4][4];
#pragma unroll
  for (int m = 0; m < 4; ++m)
#pragma unroll
    for (int n = 0; n < 4; ++n) acc[m][n] = f32x4{0.f, 0.f, 0.f, 0.f};

  uint4 ra[2], rb[2];
#pragma unroll
  for (int c = 0; c < 2; ++c) {
    ra[c] = *(const uint4*)(A + (size_t)(m0 + srow[c]) * K + sslot[c] * 8);
    rb[c] = *(const uint4*)(Bt + (size_t)(n0 + srow[c]) * K + sslot[c] * 8);
  }
#pragma unroll
  for (int c = 0; c < 2; ++c) {
    int idx = c * 256 + t;
    *(uint4*)&ldsA[0][idx * 8] = ra[c];
    *(uint4*)&ldsB[0][idx * 8] = rb[c];
  }
  __syncthreads();

  const int nt = K / 32;
  for (int tt = 0; tt < nt; ++tt) {
    const int cur = tt & 1;
    if (tt + 1 < nt) {
      const int kc = (tt + 1) * 32;
#pragma unroll
      for (int c = 0; c < 2; ++c) {
        ra[c] = *(const uint4*)(A + (size_t)(m0 + srow[c]) * K + kc + sslot[c] * 8);
        rb[c] = *(const uint4*)(Bt + (size_t)(n0 + srow[c]) * K + kc + sslot[c] * 8);
      }
    }
    bf16x8 af[4], bf[4];
#pragma unroll
    for (int m = 0; m < 4; ++m) af[m] = *(const bf16x8*)&ldsA[cur][offA[m]];
#pragma unroll
    for (int n = 0; n < 4; ++n) bf[n] = *(const bf16x8*)&ldsB[cur][offB[n]];
#pragma unroll
    for (int m = 0; m < 4; ++m)
#pragma unroll
      for (int n = 0; n < 4; ++n)
        acc[m][n] = __builtin_amdgcn_mfma_f32_16x16x32_bf16(af[m], bf[n], acc[m][n], 0, 0, 0);
    if (tt + 1 < nt) {
#pragma unroll
      for (int c = 0; c < 2; ++c) {
        int idx = c * 256 + t;
        *(uint4*)&ldsA[cur ^ 1][idx * 8] = ra[c];
        *(uint4*)&ldsB[cur ^ 1][idx * 8] = rb[c];
      }
    }
    __syncthreads();
  }

  if (EPI == 3) {
    // fused per-row LN over this tile's 128 cols (one PatchExpand group)
    __shared__ float lnS[2][128], lnQ[2][128];
    float s_[4][4], q_[4][4];
#pragma unroll
    for (int m = 0; m < 4; ++m)
#pragma unroll
      for (int j = 0; j < 4; ++j) {
        float s = 0.f, q = 0.f;
#pragma unroll
        for (int n = 0; n < 4; ++n) {
          float v = acc[m][n][j];
          s += v; q += v * v;
        }
        s_[m][j] = s; q_[m][j] = q;
      }
#pragma unroll
    for (int msk = 1; msk < 16; msk <<= 1) {
#pragma unroll
      for (int m = 0; m < 4; ++m)
#pragma unroll
        for (int j = 0; j < 4; ++j) {
          s_[m][j] += __shfl_xor(s_[m][j], msk, 64);
          q_[m][j] += __shfl_xor(q_[m][j], msk, 64);
        }
    }
    if (lrow == 0) {
#pragma unroll
      for (int m = 0; m < 4; ++m)
#pragma unroll
        for (int j = 0; j < 4; ++j) {
          int r = wr * 64 + m * 16 + kgrp * 4 + j;
          lnS[wc][r] = s_[m][j];
          lnQ[wc][r] = q_[m][j];
        }
    }
    __syncthreads();
#pragma unroll
    for (int m = 0; m < 4; ++m) {
      const int rb0 = wr * 64 + m * 16 + kgrp * 4;
#pragma unroll
      for (int j = 0; j < 4; ++j) {
        const int r = rb0 + j;
        float S = lnS[0][r] + lnS[1][r];
        float Q = lnQ[0][r] + lnQ[1][r];
        float mean = S * (1.0f / 128.0f);
        float var = Q * (1.0f / 128.0f) - mean * mean;
        float iv = rsqrtf(var + 1e-5f);
#pragma unroll
        for (int n = 0; n < 4; ++n) {
          int lc = wc * 64 + n * 16 + lrow;
          ((float*)Cout)[(size_t)(m0 + r) * Ncols + n0 + lc] =
              (acc[m][n][j] - mean) * iv * gup[lc] + beup[lc];
        }
      }
    }
    return;
  }

  float bcol[4];
#pragma unroll
  for (int n = 0; n < 4; ++n) {
    int col = n0 + wc * 64 + n * 16 + (lane & 15);
    bcol[n] = bias ? bias[col] : 0.f;
  }
#pragma unroll
  for (int m = 0; m < 4; ++m) {
    const int r0 = m0 + wr * 64 + m * 16 + kgrp * 4;
#pragma unroll
    for (int n = 0; n < 4; ++n) {
      const int col = n0 + wc * 64 + n * 16 + (lane & 15);
#pragma unroll
      for (int j = 0; j < 4; ++j) {
        float v = acc[m][n][j] + bcol[n];
        size_t idx = (size_t)(r0 + j) * Ncols + col;
        if (EPI == 0) {
          ((float*)Cout)[idx] = v;
        } else if (EPI == 1) {
          ((u16*)Cout)[idx] = f2bf(v);
        } else {
          v += bf2f(resid[idx]);
          ((u16*)Cout)[idx] = f2bf(v);
        }
      }
    }
  }
}

// ---------------- LN over 256 cols; optional bf16 row-out and bf16 transposed-out ----------------
template <bool ROWOUT, bool TOUT>
__global__ __launch_bounds__(256) void ln256x(const float* __restrict__ in,
                                              const float* __restrict__ g,
                                              const float* __restrict__ be,
                                              u16* __restrict__ rowout,
                                              u16* __restrict__ tout) {
  const int row = blockIdx.x, t = threadIdx.x;
  __shared__ float ws[8];
  float v = in[(size_t)row * DD + t];
  float s = v, q = v * v;
#pragma unroll
  for (int m = 1; m < 64; m <<= 1) {
    s += __shfl_xor(s, m, 64);
    q += __shfl_xor(q, m, 64);
  }
  if ((t & 63) == 0) { ws[t >> 6] = s; ws[4 + (t >> 6)] = q; }
  __syncthreads();
  s = ws[0] + ws[1] + ws[2] + ws[3];
  q = ws[4] + ws[5] + ws[6] + ws[7];
  float mean = s * (1.0f / DD);
  float var = q * (1.0f / DD) - mean * mean;
  float iv = rsqrtf(var + 1e-5f);
  u16 rb = f2bf((v - mean) * iv * g[t] + be[t]);
  if (ROWOUT) rowout[(size_t)row * DD + t] = rb;
  if (TOUT) {
    int b = row >> 12, n = row & 4095;
    tout[((size_t)(b * 256 + t)) * 4096 + n] = rb;
  }
}

// ------- k34: fused column-softmax stats + ctx, coalesced via n2T/n1T -------
// grid = BB*256 blocks; block (b,d): p = softmax over tokens of n2T[b][d][:],
// ctx[b,h,k=d&31,v] = sum_n p[n] * n1T[b, h*32+v, n]
__global__ __launch_bounds__(256) void k34_ctx(
    const u16* __restrict__ n2T, const u16* __restrict__ n1T,
    float* __restrict__ ctx) {
  const int bx = blockIdx.x;
  const int b = bx >> 8, d = bx & 255;
  const int h = d >> 5, kk = d & 31;
  const int t = threadIdx.x;
  __shared__ u16 prow[4096];
  __shared__ float xred[8];
  __shared__ float sw[128];
  const u16* src = n2T + (size_t)bx * 4096;
  ((uint4*)prow)[t] = ((const uint4*)src)[t];
  ((uint4*)prow)[256 + t] = ((const uint4*)src)[256 + t];
  __syncthreads();
  float mx = -1e30f;
#pragma unroll
  for (int i = 0; i < 16; ++i) mx = fmaxf(mx, bf2f(prow[i * 256 + t]));
#pragma unroll
  for (int m = 1; m < 64; m <<= 1) mx = fmaxf(mx, __shfl_xor(mx, m, 64));
  if ((t & 63) == 0) xred[t >> 6] = mx;
  __syncthreads();
  mx = fmaxf(fmaxf(xred[0], xred[1]), fmaxf(xred[2], xred[3]));
  float sme = 0.f;
#pragma unroll
  for (int i = 0; i < 16; ++i) sme += __expf(bf2f(prow[i * 256 + t]) - mx);
#pragma unroll
  for (int m = 1; m < 64; m <<= 1) sme += __shfl_xor(sme, m, 64);
  if ((t & 63) == 0) xred[4 + (t >> 6)] = sme;
  __syncthreads();
  const float inv = 1.0f / (xred[4] + xred[5] + xred[6] + xred[7]);

  float acc[32];
#pragma unroll
  for (int v = 0; v < 32; ++v) acc[v] = 0.f;
  const u16* vbase = n1T + ((size_t)(b * 256 + h * 32)) * 4096;
  for (int i = 0; i < 16; ++i) {
    const int n = i * 256 + t;
    const float p = __expf(bf2f(prow[n]) - mx) * inv;
#pragma unroll
    for (int v = 0; v < 32; ++v)
      acc[v] += p * bf2f(vbase[(size_t)v * 4096 + n]);
  }
  // wave butterfly then cross-wave
#pragma unroll
  for (int v = 0; v < 32; ++v) {
#pragma unroll
    for (int m = 1; m < 64; m <<= 1) acc[v] += __shfl_xor(acc[v], m, 64);
  }
  if ((t & 63) == 0) {
#pragma unroll
    for (int v = 0; v < 32; ++v) sw[(t >> 6) * 32 + v] = acc[v];
  }
  __syncthreads();
  if (t < 32)
    ctx[(((size_t)(b * 8 + h)) * 32 + kk) * 32 + t] =
        sw[t] + sw[32 + t] + sw[64 + t] + sw[96 + t];
}

// ---------------- k5: attT[b,n,d] = sum_k ctx * softmaxQ ----------------
__global__ __launch_bounds__(256) void k5_attT(
    const u16* __restrict__ n2, const float* __restrict__ ctx,
    u16* __restrict__ attT) {
  const int row = blockIdx.x, t = threadIdx.x;
  const int b = row >> 12;
  const int h = t >> 5, v = t & 31;
  __shared__ float nr[DD];
  __shared__ float q[DD];
  nr[t] = bf2f(n2[(size_t)row * DD + t]);
  __syncthreads();
  float mx = -1e30f;
  for (int c = 0; c < 32; ++c) mx = fmaxf(mx, nr[h * 32 + c]);
  float sm = 0.f;
  for (int c = 0; c < 32; ++c) sm += __expf(nr[h * 32 + c] - mx);
  q[t] = __expf(nr[t] - mx) / sm;
  __syncthreads();
  const float* cb = ctx + ((size_t)(b * 8 + h) * 32) * 32 + v;
  float acc = 0.f;
#pragma unroll
  for (int k = 0; k < 32; ++k) acc += cb[k * 32] * q[h * 32 + k];
  attT[(size_t)row * DD + t] = f2bf(acc);
}

// ------- l3: rep = LN(rep_raw); tx = concat(x1e,x2)+rep; txln = LN(tx) -------
__global__ __launch_bounds__(256) void l3_reptx(
    const float* __restrict__ rep_raw, const float* __restrict__ x1e,
    const float* __restrict__ x2,
    const float* __restrict__ g_an, const float* __restrict__ be_an,
    const float* __restrict__ g_n2, const float* __restrict__ be_n2,
    u16* __restrict__ tx, u16* __restrict__ txln) {
  const int row = blockIdx.x, t = threadIdx.x;
  __shared__ float ws[8];
  float a0 = rep_raw[(size_t)row * DD2 + t];
  float a1 = rep_raw[(size_t)row * DD2 + 256 + t];
  float s = a0 + a1, q = a0 * a0 + a1 * a1;
#pragma unroll
  for (int m = 1; m < 64; m <<= 1) {
    s += __shfl_xor(s, m, 64);
    q += __shfl_xor(q, m, 64);
  }
  if ((t & 63) == 0) { ws[t >> 6] = s; ws[4 + (t >> 6)] = q; }
  __syncthreads();
  s = ws[0] + ws[1] + ws[2] + ws[3];
  q = ws[4] + ws[5] + ws[6] + ws[7];
  float mean = s * (1.0f / DD2);
  float var = q * (1.0f / DD2) - mean * mean;
  float iv = rsqrtf(var + 1e-5f);
  float r0 = (a0 - mean) * iv * g_an[t] + be_an[t];
  float r1 = (a1 - mean) * iv * g_an[256 + t] + be_an[256 + t];
  float t0 = x1e[(size_t)row * DD + t] + r0;
  float t1 = x2[(size_t)row * DD + t] + r1;
  tx[(size_t)row * DD2 + t] = f2bf(t0);
  tx[(size_t)row * DD2 + 256 + t] = f2bf(t1);
  __syncthreads();  // ws reuse
  s = t0 + t1; q = t0 * t0 + t1 * t1;
#pragma unroll
  for (int m = 1; m < 64; m <<= 1) {
    s += __shfl_xor(s, m, 64);
    q += __shfl_xor(q, m, 64);
  }
  if ((t & 63) == 0) { ws[t >> 6] = s; ws[4 + (t >> 6)] = q; }
  __syncthreads();
  s = ws[0] + ws[1] + ws[2] + ws[3];
  q = ws[4] + ws[5] + ws[6] + ws[7];
  mean = s * (1.0f / DD2);
  var = q * (1.0f / DD2) - mean * mean;
  iv = rsqrtf(var + 1e-5f);
  txln[(size_t)row * DD2 + t] = f2bf((t0 - mean) * iv * g_n2[t] + be_n2[t]);
  txln[(size_t)row * DD2 + 256 + t] = f2bf((t1 - mean) * iv * g_n2[256 + t] + be_n2[256 + t]);
}

// ------- c8a: dw-conv3d + skip + LN + GELU -> ax bf16 (branch-free, 1-barrier) -------
__global__ __launch_bounds__(256) void c8a_conv(
    const u16* __restrict__ h, const float* __restrict__ w_dwt,
    const float* __restrict__ b_dw, const float* __restrict__ g,
    const float* __restrict__ be, u16* __restrict__ ax) {
  const int row = blockIdx.x, t = threadIdx.x;
  const int b = row >> 12, n = row & (NN - 1);
  const int z = n >> 8, y = (n >> 4) & 15, x = n & 15;
  const int c0 = t * 4;
  __shared__ float ws[8];
  const size_t hb = (size_t)b * NN * CC2;

  int off[27]; float msk[27];
  {
    int jj = 0;
#pragma unroll
    for (int dz = -1; dz <= 1; ++dz)
#pragma unroll
      for (int dy = -1; dy <= 1; ++dy)
#pragma unroll
        for (int dx = -1; dx <= 1; ++dx) {
          int zz = z + dz, yy = y + dy, xx = x + dx;
          bool ok = ((unsigned)zz < 16u) && ((unsigned)yy < 16u) && ((unsigned)xx < 16u);
          off[jj] = ok ? ((zz << 8) | (yy << 4) | xx) : n;
          msk[jj] = ok ? 1.f : 0.f;
          ++jj;
        }
  }
  uint2 hv[27];
#pragma unroll
  for (int j = 0; j < 27; ++j)
    hv[j] = *(const uint2*)(h + hb + (size_t)off[j] * CC2 + c0);

  float4 bv = *(const float4*)(b_dw + c0);
  float acc0 = bv.x, acc1 = bv.y, acc2 = bv.z, acc3 = bv.w;
#pragma unroll
  for (int j = 0; j < 27; ++j) {
    float4 w4 = *(const float4*)(w_dwt + j * CC2 + c0);
    float m = msk[j];
    acc0 += (m * w4.x) * u2f(hv[j].x << 16);
    acc1 += (m * w4.y) * u2f(hv[j].x & 0xffff0000u);
    acc2 += (m * w4.z) * u2f(hv[j].y << 16);
    acc3 += (m * w4.w) * u2f(hv[j].y & 0xffff0000u);
  }
  uint2 hs = *(const uint2*)(h + hb + (size_t)n * CC2 + c0);
  float v0 = acc0 + u2f(hs.x << 16), v1 = acc1 + u2f(hs.x & 0xffff0000u);
  float v2 = acc2 + u2f(hs.y << 16), v3 = acc3 + u2f(hs.y & 0xffff0000u);
  float s = v0 + v1 + v2 + v3;
  float q = v0 * v0 + v1 * v1 + v2 * v2 + v3 * v3;
#pragma unroll
  for (int m = 1; m < 64; m <<= 1) {
    s += __shfl_xor(s, m, 64);
    q += __shfl_xor(q, m, 64);
  }
  if ((t & 63) == 0) { ws[t >> 6] = s; ws[4 + (t >> 6)] = q; }
  __syncthreads();
  s = ws[0] + ws[1] + ws[2] + ws[3];
  q = ws[4] + ws[5] + ws[6] + ws[7];
  float mean = s * (1.0f / CC2);
  float var = q * (1.0f / CC2) - mean * mean;
  float iv = rsqrtf(var + 1e-5f);
  float4 gg = *(const float4*)(g + c0);
  float4 bb = *(const float4*)(be + c0);
  float vv[4] = {v0, v1, v2, v3};
  float gv[4] = {gg.x, gg.y, gg.z, gg.w};
  float bvv[4] = {bb.x, bb.y, bb.z, bb.w};
  u16 o[4];
#pragma unroll
  for (int j = 0; j < 4; ++j) {
    float u = (vv[j] - mean) * iv * gv[j] + bvv[j];
    float s2 = 1.5957691216f * (u + 0.044715f * u * u * u);
    o[j] = f2bf(u / (1.0f + __expf(-s2)));
  }
  *(uint2*)(ax + (size_t)row * CC2 + c0) = *(uint2*)o;
}

extern "C" void kernel_launch(void* const* d_in, const int* in_sizes, int n_in,
                              void* d_out, int out_size, void* d_ws, size_t ws_size,
                              hipStream_t stream) {
  const float* x1    = (const float*)d_in[0];
  const float* x2    = (const float*)d_in[1];
  const float* w_x1  = (const float*)d_in[2];
  const float* b_x1  = (const float*)d_in[3];
  const float* g_n1  = (const float*)d_in[4];
  const float* be_n1 = (const float*)d_in[5];
  const float* w_rep = (const float*)d_in[6];
  const float* b_rep = (const float*)d_in[7];
  const float* g_an  = (const float*)d_in[8];
  const float* be_an = (const float*)d_in[9];
  const float* g_n2  = (const float*)d_in[10];
  const float* be_n2 = (const float*)d_in[11];
  const float* w_fc1 = (const float*)d_in[12];
  const float* b_fc1 = (const float*)d_in[13];
  const float* w_dw  = (const float*)d_in[14];
  const float* b_dw  = (const float*)d_in[15];
  const float* g_m1  = (const float*)d_in[16];
  const float* be_m1 = (const float*)d_in[17];
  const float* w_fc2 = (const float*)d_in[18];
  const float* b_fc2 = (const float*)d_in[19];
  const float* w_cat = (const float*)d_in[20];
  const float* b_cat = (const float*)d_in[21];
  const float* w_exp = (const float*)d_in[22];
  const float* g_up  = (const float*)d_in[23];
  const float* be_up = (const float*)d_in[24];

  char* ws = (char*)d_ws;
  float* out = (float*)d_out;

  u16*   x1b     = (u16*)(ws + 0);          // 8MB; then attT; then ybuf
  float* x1e     = (float*)(ws + 8 * MB);   // 16MB f32; then mx (bf16)
  u16*   n1T     = (u16*)(ws + 24 * MB);    // 8MB
  u16*   n2b     = (u16*)(ws + 32 * MB);    // 8MB bf16 row-major
  u16*   n2T     = (u16*)(ws + 40 * MB);    // 8MB
  float* ctx     = (float*)(ws + 48 * MB);  // 128KB
  float* rep_raw = (float*)(ws + 49 * MB);  // 32MB f32; then ax (bf16)
  u16*   tx      = (u16*)(ws + 81 * MB);    // 16MB
  u16*   txln    = (u16*)(ws + 97 * MB);    // 16MB
  u16*   hbuf    = (u16*)(ws + 113 * MB);   // 32MB
  u16*   attT    = (u16*)(ws + 0);
  u16*   ax      = (u16*)(ws + 49 * MB);
  u16*   mx      = (u16*)(ws + 8 * MB);
  u16*   ybuf    = (u16*)(ws + 0);
  u16*   w_x1t   = (u16*)(ws + 145 * MB);
  u16*   w_rept  = w_x1t + 256 * 256;
  u16*   w_fc1t  = w_rept + 512 * 256;
  u16*   w_fc2t  = w_fc1t + 1024 * 512;
  u16*   w_catt  = w_fc2t + 512 * 1024;
  u16*   w_expt  = w_catt + 256 * 512;
  float* w_dwt   = (float*)(ws + 149 * MB);

  wconv_t<<<(256 * 256 + 255) / 256, 256, 0, stream>>>(w_x1, w_x1t, 256, 256);
  wconv_t<<<(256 * 512 + 255) / 256, 256, 0, stream>>>(w_rep, w_rept, 256, 512);
  wconv_t<<<(512 * 1024 + 255) / 256, 256, 0, stream>>>(w_fc1, w_fc1t, 512, 1024);
  wconv_t<<<(1024 * 512 + 255) / 256, 256, 0, stream>>>(w_fc2, w_fc2t, 1024, 512);
  wconv_t<<<(512 * 256 + 255) / 256, 256, 0, stream>>>(w_cat, w_catt, 512, 256);
  wconv_t<<<(256 * 1024 + 255) / 256, 256, 0, stream>>>(w_exp, w_expt, 256, 1024);
  wdw_t<<<(27 * CC2 + 255) / 256, 256, 0, stream>>>(w_dw, w_dwt);

  cast8<<<(ROWS * DD / 8 + 255) / 256, 256, 0, stream>>>(x1, x1b, ROWS * DD / 8);

  gemm_mfma<256, 0><<<(ROWS / 128) * 2, 256, 0, stream>>>(
      x1b, w_x1t, b_x1, nullptr, x1e, 2, nullptr, nullptr);
  ln256x<false, true><<<ROWS, 256, 0, stream>>>(x1e, g_n1, be_n1, nullptr, n1T);
  ln256x<true, true><<<ROWS, 256, 0, stream>>>(x2, g_n1, be_n1, n2b, n2T);
  k34_ctx<<<BB * 256, 256, 0, stream>>>(n2T, n1T, ctx);
  k5_attT<<<ROWS, 256, 0, stream>>>(n2b, ctx, attT);
  gemm_mfma<256, 0><<<(ROWS / 128) * 4, 256, 0, stream>>>(
      attT, w_rept, b_rep, nullptr, rep_raw, 4, nullptr, nullptr);
  l3_reptx<<<ROWS, 256, 0, stream>>>(rep_raw, x1e, x2, g_an, be_an, g_n2, be_n2, tx, txln);
  gemm_mfma<512, 1><<<(ROWS / 128) * 8, 256, 0, stream>>>(
      txln, w_fc1t, b_fc1, nullptr, hbuf, 8, nullptr, nullptr);
  c8a_conv<<<ROWS, 256, 0, stream>>>(hbuf, w_dwt, b_dw, g_m1, be_m1, ax);
  gemm_mfma<1024, 2><<<(ROWS / 128) * 4, 256, 0, stream>>>(
      ax, w_fc2t, b_fc2, tx, mx, 4, nullptr, nullptr);
  gemm_mfma<512, 1><<<(ROWS / 128) * 2, 256, 0, stream>>>(
      mx, w_catt, b_cat, nullptr, ybuf, 2, nullptr, nullptr);
  gemm_mfma<256, 3><<<(ROWS / 128) * 8, 256, 0, stream>>>(
      ybuf, w_expt, nullptr, nullptr, out, 8, g_up, be_up);
}